// Round 1
// baseline (1513.959 us; speedup 1.0000x reference)
//
#include <hip/hip_runtime.h>

#define T_ 48
#define B_ 32
#define N_ 96
#define E_ 24576
#define BN_ (B_*N_)      // 3072
#define M_ (T_*BN_)      // 147456
#define FIN_ 16
#define H_ 128
#define C_ 500
#define TE_ (T_*E_)      // 1179648
#define EPS_ 1e-5f
#define SCAN_NB (M_/256) // 576

// ---------------- graph preprocessing ----------------

__global__ void count_edges_k(const int* __restrict__ ei, int* __restrict__ cnt) {
    int i = blockIdx.x * blockDim.x + threadIdx.x;
    if (i >= TE_) return;
    int t = i / E_, e = i % E_;
    int dst = ei[(t*2+1)*E_ + e] + t*BN_;
    atomicAdd(&cnt[dst], 1);
}

__global__ void dinv_k(const int* __restrict__ cnt, float* __restrict__ dinv) {
    int i = blockIdx.x * blockDim.x + threadIdx.x;
    if (i >= M_) return;
    float deg = (float)cnt[i] + 1.0f;   // +1 self loop
    dinv[i] = rsqrtf(deg);
}

__global__ void scan1_k(const int* __restrict__ cnt, int* __restrict__ bsum) {
    __shared__ int s[256];
    int i = blockIdx.x*256 + threadIdx.x;
    s[threadIdx.x] = cnt[i];
    __syncthreads();
    for (int d = 128; d > 0; d >>= 1) {
        if (threadIdx.x < d) s[threadIdx.x] += s[threadIdx.x + d];
        __syncthreads();
    }
    if (threadIdx.x == 0) bsum[blockIdx.x] = s[0];
}

__global__ void scan2_k(const int* __restrict__ bsum, int* __restrict__ bexcl,
                        int* __restrict__ csr_off) {
    int run = 0;
    for (int i = 0; i < SCAN_NB; i++) { bexcl[i] = run; run += bsum[i]; }
    csr_off[M_] = run;
}

__global__ void scan3_k(const int* __restrict__ cnt, const int* __restrict__ bexcl,
                        int* __restrict__ csr_off) {
    __shared__ int s[256];
    int i = blockIdx.x*256 + threadIdx.x;
    int v = cnt[i];
    s[threadIdx.x] = v;
    __syncthreads();
    for (int d = 1; d < 256; d <<= 1) {
        int add = (threadIdx.x >= d) ? s[threadIdx.x - d] : 0;
        __syncthreads();
        s[threadIdx.x] += add;
        __syncthreads();
    }
    csr_off[i] = bexcl[blockIdx.x] + s[threadIdx.x] - v;  // exclusive
}

__global__ void fill_k(const int* __restrict__ ei, const int* __restrict__ csr_off,
                       int* __restrict__ cur, int* __restrict__ csr_src) {
    int i = blockIdx.x * blockDim.x + threadIdx.x;
    if (i >= TE_) return;
    int t = i / E_, e = i % E_;
    int src = ei[(t*2+0)*E_ + e] + t*BN_;
    int dst = ei[(t*2+1)*E_ + e] + t*BN_;
    int pos = atomicAdd(&cur[dst], 1);
    csr_src[csr_off[dst] + pos] = src;
}

// s[node,f] = h[node,f]/deg + sum_edges h[src,f] * dinv[src]*dinv[node]
template<int LOGF>
__global__ void gather_k(const float* __restrict__ h, float* __restrict__ s,
                         const int* __restrict__ csr_off, const int* __restrict__ csr_src,
                         const float* __restrict__ dinv) {
    const int F = 1 << LOGF;
    long total = (long)M_ * F;
    long i = (long)blockIdx.x * blockDim.x + threadIdx.x;
    if (i >= total) return;
    int f = (int)(i & (F - 1));
    int node = (int)(i >> LOGF);
    float dv = dinv[node];
    float acc = h[(long)node*F + f] * dv * dv;
    int e0 = csr_off[node], e1 = csr_off[node + 1];
    for (int j = e0; j < e1; j++) {
        int sc = csr_src[j];
        acc += h[(long)sc*F + f] * (dinv[sc] * dv);
    }
    s[i] = acc;
}

// ---------------- small prep ----------------

__global__ void prep_k(const float* __restrict__ gcn_b, const float* __restrict__ gam,
                       const float* __restrict__ bet, const float* __restrict__ mu,
                       const float* __restrict__ var,
                       float* __restrict__ bn_sc, float* __restrict__ bn_sh,
                       const float* __restrict__ bih0, const float* __restrict__ bhh0,
                       float* __restrict__ bias0,
                       const float* __restrict__ bih1, const float* __restrict__ bhh1,
                       float* __restrict__ bias1) {
    int i = blockIdx.x * blockDim.x + threadIdx.x;
    if (i < 3*H_) {
        float sc = gam[i] * rsqrtf(var[i] + EPS_);
        bn_sc[i] = sc;
        bn_sh[i] = gcn_b[i]*sc + bet[i] - mu[i]*sc;
    }
    if (i < 2*512) {
        bias0[i] = bih0[i] + bhh0[i];
        bias1[i] = bih1[i] + bhh1[i];
    }
}

__global__ void transpose_k(const float* __restrict__ in, float* __restrict__ out,
                            int R, int Cc, int nb) {
    int total = nb * R * Cc;
    for (int i = blockIdx.x * blockDim.x + threadIdx.x; i < total;
         i += gridDim.x * blockDim.x) {
        int b = i / (R * Cc);
        int rem = i - b * R * Cc;
        int r = rem / Cc, c = rem - r * Cc;
        out[(long)b*R*Cc + (long)c*R + r] = in[i];
    }
}

// ---------------- tiled matmul, fused epilogues ----------------
// C[Mr,Nc] = A[Mr,K] @ W[K,Nc]  then
//   epi==0: += bias[col]
//   epi==1: v = relu(v*bnsc[col] + bnsh[col]) (+ resid[row,col])
// Tile 32 rows x 128 cols; when Nc==128 (single col tile) C may alias A.
__global__ __launch_bounds__(256) void mm_k(
    const float* __restrict__ A, const float* __restrict__ W, float* __restrict__ C,
    int Mr, int K, int Nc, int epi,
    const float* __restrict__ bias,
    const float* __restrict__ bnsc, const float* __restrict__ bnsh,
    const float* __restrict__ resid)
{
    __shared__ float As[32][32];
    __shared__ float Ws[32][128];
    int tid = threadIdx.x;
    int ct = tid & 31;       // col group (4 cols each)
    int rt = tid >> 5;       // row group (4 rows each), 0..7
    int row0 = blockIdx.x * 32, c0 = blockIdx.y * 128;
    float acc[4][4] = {};

    for (int k0 = 0; k0 < K; k0 += 32) {
        for (int li = tid; li < 1024; li += 256) {
            int r = li >> 5, kk = li & 31;
            float v = 0.f;
            if (k0 + kk < K && row0 + r < Mr) v = A[(long)(row0 + r)*K + k0 + kk];
            As[r][kk] = v;
        }
        for (int li = tid; li < 4096; li += 256) {
            int kr = li >> 7, c = li & 127;
            float v = 0.f;
            if (k0 + kr < K && c0 + c < Nc) v = W[(long)(k0 + kr)*Nc + c0 + c];
            Ws[kr][c] = v;
        }
        __syncthreads();
        #pragma unroll
        for (int k = 0; k < 32; k++) {
            float a0 = As[rt*4+0][k], a1 = As[rt*4+1][k];
            float a2 = As[rt*4+2][k], a3 = As[rt*4+3][k];
            float4 wv = *(const float4*)&Ws[k][ct*4];
            acc[0][0] += a0*wv.x; acc[0][1] += a0*wv.y; acc[0][2] += a0*wv.z; acc[0][3] += a0*wv.w;
            acc[1][0] += a1*wv.x; acc[1][1] += a1*wv.y; acc[1][2] += a1*wv.z; acc[1][3] += a1*wv.w;
            acc[2][0] += a2*wv.x; acc[2][1] += a2*wv.y; acc[2][2] += a2*wv.z; acc[2][3] += a2*wv.w;
            acc[3][0] += a3*wv.x; acc[3][1] += a3*wv.y; acc[3][2] += a3*wv.z; acc[3][3] += a3*wv.w;
        }
        __syncthreads();
    }

    #pragma unroll
    for (int i = 0; i < 4; i++) {
        int row = row0 + rt*4 + i;
        if (row >= Mr) continue;
        float4 o;
        float* po = (float*)&o;
        #pragma unroll
        for (int u = 0; u < 4; u++) {
            int c = c0 + ct*4 + u;
            float v = acc[i][u];
            if (epi == 0) {
                if (bias) v += bias[c];
            } else {
                v = v * bnsc[c] + bnsh[c];
                v = fmaxf(v, 0.f);
                if (resid) v += resid[(long)row*Nc + c];
            }
            po[u] = v;
        }
        *(float4*)&C[(long)row*Nc + c0 + ct*4] = o;
    }
}

// ---------------- mean pool ----------------

__global__ void meanpool_k(const float* __restrict__ h, float* __restrict__ emb) {
    int row = blockIdx.x;            // t*B + b
    int t = row / B_, b = row - t*B_;
    int hh = threadIdx.x;
    const float* base = h + ((long)t*BN_ + b*N_)*H_ + hh;
    float acc = 0.f;
    for (int n = 0; n < N_; n++) acc += base[(long)n*H_];
    emb[(long)row*H_ + hh] = acc * (1.f / N_);
}

// ---------------- LSTM scan ----------------
// grid = 2 dirs * (B/BC) blocks, 512 threads. Each block owns BC batch rows.
#define BC_ 2
__global__ __launch_bounds__(512) void lstm_scan_k(
    const float* __restrict__ pre,    // [2][T*B][512] (bih+bhh already added)
    const float* __restrict__ whh_t,  // [2][128][512]
    float* __restrict__ out)          // [T*B][256]; dir0 -> [0:128), dir1 -> [128:256)
{
    int bid = blockIdx.x;
    int dir = bid / (B_/BC_);
    int b0  = (bid % (B_/BC_)) * BC_;
    int g = threadIdx.x;             // 0..511 (gate-major)
    int q = g >> 7, hidx = g & 127;
    __shared__ float h_s[BC_][H_];
    __shared__ float c_s[BC_][H_];
    __shared__ float gbuf[4][BC_][H_];

    if (g < BC_*H_) { h_s[g>>7][g&127] = 0.f; c_s[g>>7][g&127] = 0.f; }
    __syncthreads();

    const float* whh  = whh_t + (long)dir * H_ * 512;
    const float* pred = pre   + (long)dir * T_ * B_ * 512;

    for (int st = 0; st < T_; st++) {
        int t = dir ? (T_ - 1 - st) : st;
        float acc0 = 0.f, acc1 = 0.f;
        #pragma unroll 8
        for (int k = 0; k < H_; k++) {
            float wv = whh[k*512 + g];
            acc0 += h_s[0][k] * wv;
            acc1 += h_s[1][k] * wv;
        }
        gbuf[q][0][hidx] = acc0 + pred[((long)t*B_ + b0 + 0)*512 + g];
        gbuf[q][1][hidx] = acc1 + pred[((long)t*B_ + b0 + 1)*512 + g];
        __syncthreads();
        if (g < BC_*H_) {
            int b = g >> 7, hh = g & 127;
            float ig = 1.f / (1.f + __expf(-gbuf[0][b][hh]));
            float fg = 1.f / (1.f + __expf(-gbuf[1][b][hh]));
            float gg = tanhf(gbuf[2][b][hh]);
            float og = 1.f / (1.f + __expf(-gbuf[3][b][hh]));
            float c = fg * c_s[b][hh] + ig * gg;
            float h = og * tanhf(c);
            c_s[b][hh] = c; h_s[b][hh] = h;
            out[((long)t*B_ + b0 + b)*256 + dir*H_ + hh] = h;
        }
        __syncthreads();
    }
}

// ---------------- attention ----------------

__global__ __launch_bounds__(128) void attn_a_k(
    const float* __restrict__ out2, const float* __restrict__ w1,
    const float* __restrict__ b1, const float* __restrict__ w2,
    const float* __restrict__ b2v, float* __restrict__ a)
{
    int row = blockIdx.x;            // t*B + b
    int j = threadIdx.x;
    const float* xr = out2 + (long)row * 256;
    float acc = b1[j];
    for (int k = 0; k < 256; k++) acc += xr[k] * w1[k*128 + j];
    float u = tanhf(acc) * w2[j];
    __shared__ float red[128];
    red[j] = u;
    __syncthreads();
    for (int d = 64; d > 0; d >>= 1) {
        if (j < d) red[j] += red[j + d];
        __syncthreads();
    }
    if (j == 0) {
        int t = row / B_, b = row - t*B_;
        a[b*T_ + t] = red[0] + b2v[0];
    }
}

__global__ __launch_bounds__(256) void attn_pool_k(
    const float* __restrict__ out2, const float* __restrict__ a,
    float* __restrict__ wsv)
{
    int b = blockIdx.x;
    __shared__ float w[T_];
    if (threadIdx.x == 0) {
        float m = -1e30f;
        for (int t = 0; t < T_; t++) m = fmaxf(m, a[b*T_ + t]);
        float s = 0.f;
        for (int t = 0; t < T_; t++) { float e = __expf(a[b*T_ + t] - m); w[t] = e; s += e; }
        float inv = 1.f / s;
        for (int t = 0; t < T_; t++) w[t] *= inv;
    }
    __syncthreads();
    int h2 = threadIdx.x;            // 0..255
    float acc = 0.f;
    for (int t = 0; t < T_; t++) acc += w[t] * out2[((long)t*B_ + b)*256 + h2];
    wsv[b*256 + h2] = acc;
}

// ---------------- FC head + log_softmax ----------------

__global__ __launch_bounds__(512) void head_k(
    const float* __restrict__ wsv, const float* __restrict__ w1,
    const float* __restrict__ b1, const float* __restrict__ w2,
    const float* __restrict__ b2, float* __restrict__ outp)
{
    int b = blockIdx.x;
    int tid = threadIdx.x;
    __shared__ float r[128];
    __shared__ float y[C_];
    __shared__ float red[512];
    if (tid < 128) {
        float acc = b1[tid];
        for (int k = 0; k < 256; k++) acc += wsv[b*256 + k] * w1[k*128 + tid];
        r[tid] = fmaxf(acc, 0.f);
    }
    __syncthreads();
    for (int c = tid; c < C_; c += 512) {
        float acc = b2[c];
        for (int k = 0; k < 128; k++) acc += r[k] * w2[k*C_ + c];
        y[c] = acc;
    }
    __syncthreads();
    float m = -1e30f;
    for (int c = tid; c < C_; c += 512) m = fmaxf(m, y[c]);
    red[tid] = m;
    __syncthreads();
    for (int d = 256; d > 0; d >>= 1) {
        if (tid < d) red[tid] = fmaxf(red[tid], red[tid + d]);
        __syncthreads();
    }
    m = red[0];
    __syncthreads();
    float s = 0.f;
    for (int c = tid; c < C_; c += 512) s += __expf(y[c] - m);
    red[tid] = s;
    __syncthreads();
    for (int d = 256; d > 0; d >>= 1) {
        if (tid < d) red[tid] += red[tid + d];
        __syncthreads();
    }
    float lse = m + logf(red[0]);
    for (int c = tid; c < C_; c += 512) outp[(long)b*C_ + c] = y[c] - lse;
}

// ---------------- launch ----------------

extern "C" void kernel_launch(void* const* d_in, const int* in_sizes, int n_in,
                              void* d_out, int out_size, void* d_ws, size_t ws_size,
                              hipStream_t stream) {
    const float* x        = (const float*)d_in[0];
    const int*   ei       = (const int*)d_in[1];
    const float* gcn_w0   = (const float*)d_in[2];
    const float* gcn_w12  = (const float*)d_in[3];
    const float* gcn_b    = (const float*)d_in[4];
    const float* bn_gamma = (const float*)d_in[5];
    const float* bn_beta  = (const float*)d_in[6];
    const float* bn_mean  = (const float*)d_in[7];
    const float* bn_var   = (const float*)d_in[8];
    const float* wih0     = (const float*)d_in[9];
    const float* whh0     = (const float*)d_in[10];
    const float* bih0     = (const float*)d_in[11];
    const float* bhh0     = (const float*)d_in[12];
    const float* wih1     = (const float*)d_in[13];
    const float* whh1     = (const float*)d_in[14];
    const float* bih1     = (const float*)d_in[15];
    const float* bhh1     = (const float*)d_in[16];
    const float* attn_w1  = (const float*)d_in[17];
    const float* attn_b1  = (const float*)d_in[18];
    const float* attn_w2  = (const float*)d_in[19];
    const float* attn_b2  = (const float*)d_in[20];
    const float* fc1_w    = (const float*)d_in[21];
    const float* fc1_b    = (const float*)d_in[22];
    const float* fc2_w    = (const float*)d_in[23];
    const float* fc2_b    = (const float*)d_in[24];

    char* p = (char*)d_ws;
    auto alloc = [&](size_t bytes) {
        void* r = (void*)p;
        p += (bytes + 255) & ~(size_t)255;
        return r;
    };
    float* bufA    = (float*)alloc((size_t)M_*H_*4);
    float* bufB    = (float*)alloc((size_t)M_*H_*4);
    int*   cnt     = (int*)  alloc((size_t)M_*4);
    float* dinv    = (float*)alloc((size_t)M_*4);
    int*   bsum    = (int*)  alloc((size_t)SCAN_NB*4);
    int*   bexcl   = (int*)  alloc((size_t)SCAN_NB*4);
    int*   csr_off = (int*)  alloc((size_t)(M_+1)*4);
    int*   csr_cur = (int*)  alloc((size_t)M_*4);
    int*   csr_src = (int*)  alloc((size_t)TE_*4);
    float* bn_sc   = (float*)alloc(384*4);
    float* bn_sh   = (float*)alloc(384*4);
    float* bias0   = (float*)alloc(1024*4);
    float* bias1   = (float*)alloc(1024*4);
    float* whh0_t  = (float*)alloc((size_t)2*H_*512*4);
    float* whh1_t  = (float*)alloc((size_t)2*H_*512*4);
    float* wih0_t  = (float*)alloc((size_t)2*H_*512*4);
    float* wih1_t  = (float*)alloc((size_t)2*256*512*4);
    float* emb     = (float*)alloc((size_t)T_*B_*H_*4);
    float* pre     = (float*)alloc((size_t)2*T_*B_*512*4);
    float* out1    = (float*)alloc((size_t)T_*B_*256*4);
    float* out2v   = (float*)alloc((size_t)T_*B_*256*4);
    float* attn_av = (float*)alloc((size_t)B_*T_*4);
    float* wsv     = (float*)alloc((size_t)B_*256*4);

    // --- graph preprocessing (CSR by dst) ---
    hipMemsetAsync(cnt, 0, (size_t)M_*4, stream);
    hipMemsetAsync(csr_cur, 0, (size_t)M_*4, stream);
    count_edges_k<<<(TE_+255)/256, 256, 0, stream>>>(ei, cnt);
    dinv_k<<<(M_+255)/256, 256, 0, stream>>>(cnt, dinv);
    scan1_k<<<SCAN_NB, 256, 0, stream>>>(cnt, bsum);
    scan2_k<<<1, 1, 0, stream>>>(bsum, bexcl, csr_off);
    scan3_k<<<SCAN_NB, 256, 0, stream>>>(cnt, bexcl, csr_off);
    fill_k<<<(TE_+255)/256, 256, 0, stream>>>(ei, csr_off, csr_cur, csr_src);

    // --- weight prep ---
    prep_k<<<4, 256, 0, stream>>>(gcn_b, bn_gamma, bn_beta, bn_mean, bn_var,
                                  bn_sc, bn_sh, bih0, bhh0, bias0, bih1, bhh1, bias1);
    transpose_k<<<256, 256, 0, stream>>>(whh0, whh0_t, 512, 128, 2);
    transpose_k<<<256, 256, 0, stream>>>(whh1, whh1_t, 512, 128, 2);
    transpose_k<<<256, 256, 0, stream>>>(wih0, wih0_t, 512, 128, 2);
    transpose_k<<<256, 256, 0, stream>>>(wih1, wih1_t, 512, 256, 2);

    // --- GCN layer 0: agg(x) [M,16] -> s (bufA), mm -> bufB ---
    gather_k<4><<<(int)(((long)M_*16 + 255)/256), 256, 0, stream>>>(x, bufA, csr_off, csr_src, dinv);
    mm_k<<<dim3(M_/32, 1), 256, 0, stream>>>(bufA, gcn_w0, bufB, M_, 16, 128, 1,
                                             nullptr, bn_sc + 0, bn_sh + 0, nullptr);
    // --- GCN layer 1: agg(bufB) -> bufA, mm in-place bufA (+res bufB) ---
    gather_k<7><<<(int)(((long)M_*128 + 255)/256), 256, 0, stream>>>(bufB, bufA, csr_off, csr_src, dinv);
    mm_k<<<dim3(M_/32, 1), 256, 0, stream>>>(bufA, gcn_w12 + 0, bufA, M_, 128, 128, 1,
                                             nullptr, bn_sc + 128, bn_sh + 128, bufB);
    // --- GCN layer 2: agg(bufA) -> bufB, mm in-place bufB (+res bufA) ---
    gather_k<7><<<(int)(((long)M_*128 + 255)/256), 256, 0, stream>>>(bufA, bufB, csr_off, csr_src, dinv);
    mm_k<<<dim3(M_/32, 1), 256, 0, stream>>>(bufB, gcn_w12 + 128*128, bufB, M_, 128, 128, 1,
                                             nullptr, bn_sc + 256, bn_sh + 256, bufA);

    // --- mean pool -> emb [T*B,128] ---
    meanpool_k<<<T_*B_, 128, 0, stream>>>(bufB, emb);

    // --- BiLSTM layer 0 ---
    for (int dir = 0; dir < 2; dir++) {
        mm_k<<<dim3((T_*B_)/32, 4), 256, 0, stream>>>(
            emb, wih0_t + (size_t)dir*H_*512, pre + (size_t)dir*T_*B_*512,
            T_*B_, 128, 512, 0, bias0 + dir*512, nullptr, nullptr, nullptr);
    }
    lstm_scan_k<<<2*(B_/BC_), 512, 0, stream>>>(pre, whh0_t, out1);

    // --- BiLSTM layer 1 ---
    for (int dir = 0; dir < 2; dir++) {
        mm_k<<<dim3((T_*B_)/32, 4), 256, 0, stream>>>(
            out1, wih1_t + (size_t)dir*256*512, pre + (size_t)dir*T_*B_*512,
            T_*B_, 256, 512, 0, bias1 + dir*512, nullptr, nullptr, nullptr);
    }
    lstm_scan_k<<<2*(B_/BC_), 512, 0, stream>>>(pre, whh1_t, out2v);

    // --- attention ---
    attn_a_k<<<T_*B_, 128, 0, stream>>>(out2v, attn_w1, attn_b1, attn_w2, attn_b2, attn_av);
    attn_pool_k<<<B_, 256, 0, stream>>>(out2v, attn_av, wsv);

    // --- head ---
    head_k<<<B_, 512, 0, stream>>>(wsv, fc1_w, fc1_b, fc2_w, fc2_b, (float*)d_out);
}

// Round 2
// 962.514 us; speedup vs baseline: 1.5729x; 1.5729x over previous
//
#include <hip/hip_runtime.h>

#define T_ 48
#define B_ 32
#define N_ 96
#define E_ 24576
#define BN_ (B_*N_)      // 3072
#define M_ (T_*BN_)      // 147456
#define FIN_ 16
#define H_ 128
#define C_ 500
#define TE_ (T_*E_)      // 1179648
#define EPS_ 1e-5f
#define SCAN_NB (M_/256) // 576

typedef __bf16 bf16x8 __attribute__((ext_vector_type(8)));
typedef float  f32x4  __attribute__((ext_vector_type(4)));

__device__ __forceinline__ float bf2f(ushort u) {
    union { unsigned int i; float f; } v;
    v.i = ((unsigned int)u) << 16;
    return v.f;
}
__device__ __forceinline__ ushort f2bf(float f) {
    union { float f; unsigned int i; } v;
    v.f = f;
    unsigned int u = v.i;
    unsigned int r = (u + 0x7fffu + ((u >> 16) & 1u)) >> 16;
    return (ushort)r;
}

// ---------------- graph preprocessing ----------------

__global__ void count_edges_k(const int* __restrict__ ei, int* __restrict__ cnt) {
    int i = blockIdx.x * blockDim.x + threadIdx.x;
    if (i >= TE_) return;
    int t = i / E_, e = i % E_;
    int dst = ei[(t*2+1)*E_ + e] + t*BN_;
    atomicAdd(&cnt[dst], 1);
}

__global__ void dinv_k(const int* __restrict__ cnt, float* __restrict__ dinv) {
    int i = blockIdx.x * blockDim.x + threadIdx.x;
    if (i >= M_) return;
    float deg = (float)cnt[i] + 1.0f;   // +1 self loop
    dinv[i] = rsqrtf(deg);
}

__global__ void scan1_k(const int* __restrict__ cnt, int* __restrict__ bsum) {
    __shared__ int s[256];
    int i = blockIdx.x*256 + threadIdx.x;
    s[threadIdx.x] = cnt[i];
    __syncthreads();
    for (int d = 128; d > 0; d >>= 1) {
        if (threadIdx.x < d) s[threadIdx.x] += s[threadIdx.x + d];
        __syncthreads();
    }
    if (threadIdx.x == 0) bsum[blockIdx.x] = s[0];
}

__global__ void scan2_k(const int* __restrict__ bsum, int* __restrict__ bexcl,
                        int* __restrict__ csr_off) {
    int run = 0;
    for (int i = 0; i < SCAN_NB; i++) { bexcl[i] = run; run += bsum[i]; }
    csr_off[M_] = run;
}

__global__ void scan3_k(const int* __restrict__ cnt, const int* __restrict__ bexcl,
                        int* __restrict__ csr_off) {
    __shared__ int s[256];
    int i = blockIdx.x*256 + threadIdx.x;
    int v = cnt[i];
    s[threadIdx.x] = v;
    __syncthreads();
    for (int d = 1; d < 256; d <<= 1) {
        int add = (threadIdx.x >= d) ? s[threadIdx.x - d] : 0;
        __syncthreads();
        s[threadIdx.x] += add;
        __syncthreads();
    }
    csr_off[i] = bexcl[blockIdx.x] + s[threadIdx.x] - v;  // exclusive
}

__global__ void fill_k(const int* __restrict__ ei, const int* __restrict__ csr_off,
                       int* __restrict__ cur, int* __restrict__ csr_src) {
    int i = blockIdx.x * blockDim.x + threadIdx.x;
    if (i >= TE_) return;
    int t = i / E_, e = i % E_;
    int src = ei[(t*2+0)*E_ + e] + t*BN_;
    int dst = ei[(t*2+1)*E_ + e] + t*BN_;
    int pos = atomicAdd(&cur[dst], 1);
    csr_src[csr_off[dst] + pos] = src;
}

// ---------------- conversions / weight prep ----------------

__global__ void convx_k(const float* __restrict__ in, ushort* __restrict__ out) {
    int i = blockIdx.x * blockDim.x + threadIdx.x;   // one per 4 elems
    if (i >= M_*FIN_/4) return;
    float4 v = *(const float4*)&in[i*4];
    ushort4 o;
    o.x = f2bf(v.x); o.y = f2bf(v.y); o.z = f2bf(v.z); o.w = f2bf(v.w);
    *(ushort4*)&out[i*4] = o;
}

// in f32 [K,N] -> out bf16 col-major [N][K]
__global__ void convw_k(const float* __restrict__ in, ushort* __restrict__ out,
                        int K, int Nn) {
    int i = blockIdx.x * blockDim.x + threadIdx.x;
    if (i >= K*Nn) return;
    int k = i / Nn, c = i - k*Nn;
    out[c*K + k] = f2bf(in[i]);
}

__global__ void prep_k(const float* __restrict__ gcn_b, const float* __restrict__ gam,
                       const float* __restrict__ bet, const float* __restrict__ mu,
                       const float* __restrict__ var,
                       float* __restrict__ bn_sc, float* __restrict__ bn_sh,
                       const float* __restrict__ bih0, const float* __restrict__ bhh0,
                       float* __restrict__ bias0,
                       const float* __restrict__ bih1, const float* __restrict__ bhh1,
                       float* __restrict__ bias1) {
    int i = blockIdx.x * blockDim.x + threadIdx.x;
    if (i < 3*H_) {
        float sc = gam[i] * rsqrtf(var[i] + EPS_);
        bn_sc[i] = sc;
        bn_sh[i] = gcn_b[i]*sc + bet[i] - mu[i]*sc;
    }
    if (i < 2*512) {
        bias0[i] = bih0[i] + bhh0[i];
        bias1[i] = bih1[i] + bhh1[i];
    }
}

__global__ void transpose_k(const float* __restrict__ in, float* __restrict__ out,
                            int R, int Cc, int nb) {
    int total = nb * R * Cc;
    for (int i = blockIdx.x * blockDim.x + threadIdx.x; i < total;
         i += gridDim.x * blockDim.x) {
        int b = i / (R * Cc);
        int rem = i - b * R * Cc;
        int r = rem / Cc, c = rem - r * Cc;
        out[(long)b*R*Cc + (long)c*R + r] = in[i];
    }
}

// ---------------- bf16 gathers (XCD-chunk swizzled) ----------------
// out[node,:] = h[node,:]*dinv[node]^2 + sum_e h[src,:]*dinv[src]*dinv[node]

// F=128: 8 nodes/block, 32 lanes/node, ushort4 per lane
__global__ __launch_bounds__(256) void gather128_k(
    const ushort* __restrict__ h, ushort* __restrict__ out,
    const int* __restrict__ csr_off, const int* __restrict__ csr_src,
    const float* __restrict__ dinv)
{
    int nb = gridDim.x;                  // M/8, divisible by 8
    int chunk = nb >> 3;
    int bswz = (blockIdx.x & 7) * chunk + (blockIdx.x >> 3);
    int node = bswz * 8 + (threadIdx.x >> 5);
    int l = threadIdx.x & 31;            // f0 = l*4
    float dv = dinv[node];
    const ushort* hr = h + (long)node*128 + l*4;
    ushort4 sv = *(const ushort4*)hr;
    float s = dv * dv;
    float a0 = bf2f(sv.x)*s, a1 = bf2f(sv.y)*s, a2 = bf2f(sv.z)*s, a3 = bf2f(sv.w)*s;
    int e0 = csr_off[node], e1 = csr_off[node+1];
    for (int j = e0; j < e1; j++) {
        int sc = csr_src[j];
        float en = dinv[sc] * dv;
        ushort4 v = *(const ushort4*)(h + (long)sc*128 + l*4);
        a0 += bf2f(v.x)*en; a1 += bf2f(v.y)*en; a2 += bf2f(v.z)*en; a3 += bf2f(v.w)*en;
    }
    ushort4 o;
    o.x = f2bf(a0); o.y = f2bf(a1); o.z = f2bf(a2); o.w = f2bf(a3);
    *(ushort4*)(out + (long)node*128 + l*4) = o;
}

// F=16: 32 nodes/block, 8 lanes/node, ushort2 per lane
__global__ __launch_bounds__(256) void gather16_k(
    const ushort* __restrict__ h, ushort* __restrict__ out,
    const int* __restrict__ csr_off, const int* __restrict__ csr_src,
    const float* __restrict__ dinv)
{
    int nb = gridDim.x;                  // M/32
    int chunk = nb >> 3;
    int bswz = (blockIdx.x & 7) * chunk + (blockIdx.x >> 3);
    int node = bswz * 32 + (threadIdx.x >> 3);
    int l = threadIdx.x & 7;             // f0 = l*2
    float dv = dinv[node];
    ushort2 sv = *(const ushort2*)(h + (long)node*16 + l*2);
    float s = dv * dv;
    float a0 = bf2f(sv.x)*s, a1 = bf2f(sv.y)*s;
    int e0 = csr_off[node], e1 = csr_off[node+1];
    for (int j = e0; j < e1; j++) {
        int sc = csr_src[j];
        float en = dinv[sc] * dv;
        ushort2 v = *(const ushort2*)(h + (long)sc*16 + l*2);
        a0 += bf2f(v.x)*en; a1 += bf2f(v.y)*en;
    }
    ushort2 o;
    o.x = f2bf(a0); o.y = f2bf(a1);
    *(ushort2*)(out + (long)node*16 + l*2) = o;
}

// ---------------- MFMA GEMM: C = relu(bn(A@W)) (+resid), bf16 ----------------
// A [Mr,K] bf16 row-major; Wt [128][K] bf16 (col-major W); C [Mr,128] bf16.
// Block: 256 thr = 4 waves; BM=64 (wave w -> rows w*16..w*16+15), BN=128.
template<int K, bool HASRES>
__global__ __launch_bounds__(256) void mm_mfma_k(
    const ushort* __restrict__ A, const ushort* __restrict__ Wt,
    ushort* __restrict__ Cout,
    const float* __restrict__ bnsc, const float* __restrict__ bnsh,
    const ushort* __restrict__ resid)
{
    int tid = threadIdx.x;
    int w = tid >> 6, lane = tid & 63;
    int l16 = lane & 15, lh = lane >> 4;     // lh 0..3
    int row0 = blockIdx.x * 64 + w * 16;

    f32x4 acc[8];
    #pragma unroll
    for (int i = 0; i < 8; i++) acc[i] = (f32x4){0.f, 0.f, 0.f, 0.f};

    #pragma unroll
    for (int k0 = 0; k0 < K; k0 += 32) {
        int ka = k0 + lh*8;
        bf16x8 af;
        bool valid = (K >= 32) || (ka < K);
        if (valid) {
            af = *reinterpret_cast<const bf16x8*>(&A[(long)(row0 + l16)*K + ka]);
        } else {
            #pragma unroll
            for (int e = 0; e < 8; e++) af[e] = (__bf16)0.f;
        }
        #pragma unroll
        for (int ct = 0; ct < 8; ct++) {
            bf16x8 bfr;
            if (valid) {
                bfr = *reinterpret_cast<const bf16x8*>(&Wt[(long)(ct*16 + l16)*K + ka]);
            } else {
                #pragma unroll
                for (int e = 0; e < 8; e++) bfr[e] = (__bf16)0.f;
            }
            acc[ct] = __builtin_amdgcn_mfma_f32_16x16x32_bf16(af, bfr, acc[ct], 0, 0, 0);
        }
    }

    #pragma unroll
    for (int ct = 0; ct < 8; ct++) {
        int col = ct*16 + l16;
        float sc = bnsc[col], sh = bnsh[col];
        #pragma unroll
        for (int r = 0; r < 4; r++) {
            int row = row0 + lh*4 + r;
            float v = acc[ct][r] * sc + sh;
            v = fmaxf(v, 0.f);
            if (HASRES) v += bf2f(resid[(long)row*128 + col]);
            Cout[(long)row*128 + col] = f2bf(v);
        }
    }
}

// ---------------- f32 tiled matmul (LSTM input projections) ----------------
__global__ __launch_bounds__(256) void mm_k(
    const float* __restrict__ A, const float* __restrict__ W, float* __restrict__ C,
    int Mr, int K, int Nc, const float* __restrict__ bias)
{
    __shared__ float As[32][32];
    __shared__ float Ws[32][128];
    int tid = threadIdx.x;
    int ct = tid & 31;
    int rt = tid >> 5;
    int row0 = blockIdx.x * 32, c0 = blockIdx.y * 128;
    float acc[4][4] = {};

    for (int k0 = 0; k0 < K; k0 += 32) {
        for (int li = tid; li < 1024; li += 256) {
            int r = li >> 5, kk = li & 31;
            float v = 0.f;
            if (k0 + kk < K && row0 + r < Mr) v = A[(long)(row0 + r)*K + k0 + kk];
            As[r][kk] = v;
        }
        for (int li = tid; li < 4096; li += 256) {
            int kr = li >> 7, c = li & 127;
            float v = 0.f;
            if (k0 + kr < K && c0 + c < Nc) v = W[(long)(k0 + kr)*Nc + c0 + c];
            Ws[kr][c] = v;
        }
        __syncthreads();
        #pragma unroll
        for (int k = 0; k < 32; k++) {
            float a0 = As[rt*4+0][k], a1 = As[rt*4+1][k];
            float a2 = As[rt*4+2][k], a3 = As[rt*4+3][k];
            float4 wv = *(const float4*)&Ws[k][ct*4];
            acc[0][0] += a0*wv.x; acc[0][1] += a0*wv.y; acc[0][2] += a0*wv.z; acc[0][3] += a0*wv.w;
            acc[1][0] += a1*wv.x; acc[1][1] += a1*wv.y; acc[1][2] += a1*wv.z; acc[1][3] += a1*wv.w;
            acc[2][0] += a2*wv.x; acc[2][1] += a2*wv.y; acc[2][2] += a2*wv.z; acc[2][3] += a2*wv.w;
            acc[3][0] += a3*wv.x; acc[3][1] += a3*wv.y; acc[3][2] += a3*wv.z; acc[3][3] += a3*wv.w;
        }
        __syncthreads();
    }

    #pragma unroll
    for (int i = 0; i < 4; i++) {
        int row = row0 + rt*4 + i;
        if (row >= Mr) continue;
        float4 o;
        float* po = (float*)&o;
        #pragma unroll
        for (int u = 0; u < 4; u++) {
            int c = c0 + ct*4 + u;
            float v = acc[i][u];
            if (bias) v += bias[c];
            po[u] = v;
        }
        *(float4*)&C[(long)row*Nc + c0 + ct*4] = o;
    }
}

// ---------------- mean pool (bf16 in, f32 out) ----------------

__global__ void meanpool_k(const ushort* __restrict__ h, float* __restrict__ emb) {
    int row = blockIdx.x;            // t*B + b
    int t = row / B_, b = row - t*B_;
    int hh = threadIdx.x;
    const ushort* base = h + ((long)t*BN_ + b*N_)*H_ + hh;
    float acc = 0.f;
    for (int n = 0; n < N_; n++) acc += bf2f(base[(long)n*H_]);
    emb[(long)row*H_ + hh] = acc * (1.f / N_);
}

// ---------------- LSTM scan ----------------
#define BC_ 2
__global__ __launch_bounds__(512) void lstm_scan_k(
    const float* __restrict__ pre,    // [2][T*B][512]
    const float* __restrict__ whh_t,  // [2][128][512]
    float* __restrict__ out)          // [T*B][256]
{
    int bid = blockIdx.x;
    int dir = bid / (B_/BC_);
    int b0  = (bid % (B_/BC_)) * BC_;
    int g = threadIdx.x;
    int q = g >> 7, hidx = g & 127;
    __shared__ float h_s[BC_][H_];
    __shared__ float c_s[BC_][H_];
    __shared__ float gbuf[4][BC_][H_];

    if (g < BC_*H_) { h_s[g>>7][g&127] = 0.f; c_s[g>>7][g&127] = 0.f; }
    __syncthreads();

    const float* whh  = whh_t + (long)dir * H_ * 512;
    const float* pred = pre   + (long)dir * T_ * B_ * 512;

    for (int st = 0; st < T_; st++) {
        int t = dir ? (T_ - 1 - st) : st;
        float acc0 = 0.f, acc1 = 0.f;
        #pragma unroll 8
        for (int k = 0; k < H_; k++) {
            float wv = whh[k*512 + g];
            acc0 += h_s[0][k] * wv;
            acc1 += h_s[1][k] * wv;
        }
        gbuf[q][0][hidx] = acc0 + pred[((long)t*B_ + b0 + 0)*512 + g];
        gbuf[q][1][hidx] = acc1 + pred[((long)t*B_ + b0 + 1)*512 + g];
        __syncthreads();
        if (g < BC_*H_) {
            int b = g >> 7, hh = g & 127;
            float ig = 1.f / (1.f + __expf(-gbuf[0][b][hh]));
            float fg = 1.f / (1.f + __expf(-gbuf[1][b][hh]));
            float gg = tanhf(gbuf[2][b][hh]);
            float og = 1.f / (1.f + __expf(-gbuf[3][b][hh]));
            float c = fg * c_s[b][hh] + ig * gg;
            float h = og * tanhf(c);
            c_s[b][hh] = c; h_s[b][hh] = h;
            out[((long)t*B_ + b0 + b)*256 + dir*H_ + hh] = h;
        }
        __syncthreads();
    }
}

// ---------------- attention ----------------

__global__ __launch_bounds__(128) void attn_a_k(
    const float* __restrict__ out2, const float* __restrict__ w1,
    const float* __restrict__ b1, const float* __restrict__ w2,
    const float* __restrict__ b2v, float* __restrict__ a)
{
    int row = blockIdx.x;
    int j = threadIdx.x;
    const float* xr = out2 + (long)row * 256;
    float acc = b1[j];
    for (int k = 0; k < 256; k++) acc += xr[k] * w1[k*128 + j];
    float u = tanhf(acc) * w2[j];
    __shared__ float red[128];
    red[j] = u;
    __syncthreads();
    for (int d = 64; d > 0; d >>= 1) {
        if (j < d) red[j] += red[j + d];
        __syncthreads();
    }
    if (j == 0) {
        int t = row / B_, b = row - t*B_;
        a[b*T_ + t] = red[0] + b2v[0];
    }
}

__global__ __launch_bounds__(256) void attn_pool_k(
    const float* __restrict__ out2, const float* __restrict__ a,
    float* __restrict__ wsv)
{
    int b = blockIdx.x;
    __shared__ float w[T_];
    if (threadIdx.x == 0) {
        float m = -1e30f;
        for (int t = 0; t < T_; t++) m = fmaxf(m, a[b*T_ + t]);
        float s = 0.f;
        for (int t = 0; t < T_; t++) { float e = __expf(a[b*T_ + t] - m); w[t] = e; s += e; }
        float inv = 1.f / s;
        for (int t = 0; t < T_; t++) w[t] *= inv;
    }
    __syncthreads();
    int h2 = threadIdx.x;
    float acc = 0.f;
    for (int t = 0; t < T_; t++) acc += w[t] * out2[((long)t*B_ + b)*256 + h2];
    wsv[b*256 + h2] = acc;
}

// ---------------- FC head + log_softmax ----------------

__global__ __launch_bounds__(512) void head_k(
    const float* __restrict__ wsv, const float* __restrict__ w1,
    const float* __restrict__ b1, const float* __restrict__ w2,
    const float* __restrict__ b2, float* __restrict__ outp)
{
    int b = blockIdx.x;
    int tid = threadIdx.x;
    __shared__ float r[128];
    __shared__ float y[C_];
    __shared__ float red[512];
    if (tid < 128) {
        float acc = b1[tid];
        for (int k = 0; k < 256; k++) acc += wsv[b*256 + k] * w1[k*128 + tid];
        r[tid] = fmaxf(acc, 0.f);
    }
    __syncthreads();
    for (int c = tid; c < C_; c += 512) {
        float acc = b2[c];
        for (int k = 0; k < 128; k++) acc += r[k] * w2[k*C_ + c];
        y[c] = acc;
    }
    __syncthreads();
    float m = -1e30f;
    for (int c = tid; c < C_; c += 512) m = fmaxf(m, y[c]);
    red[tid] = m;
    __syncthreads();
    for (int d = 256; d > 0; d >>= 1) {
        if (tid < d) red[tid] = fmaxf(red[tid], red[tid + d]);
        __syncthreads();
    }
    m = red[0];
    __syncthreads();
    float s = 0.f;
    for (int c = tid; c < C_; c += 512) s += __expf(y[c] - m);
    red[tid] = s;
    __syncthreads();
    for (int d = 256; d > 0; d >>= 1) {
        if (tid < d) red[tid] += red[tid + d];
        __syncthreads();
    }
    float lse = m + logf(red[0]);
    for (int c = tid; c < C_; c += 512) outp[(long)b*C_ + c] = y[c] - lse;
}

// ---------------- launch ----------------

extern "C" void kernel_launch(void* const* d_in, const int* in_sizes, int n_in,
                              void* d_out, int out_size, void* d_ws, size_t ws_size,
                              hipStream_t stream) {
    const float* x        = (const float*)d_in[0];
    const int*   ei       = (const int*)d_in[1];
    const float* gcn_w0   = (const float*)d_in[2];
    const float* gcn_w12  = (const float*)d_in[3];
    const float* gcn_b    = (const float*)d_in[4];
    const float* bn_gamma = (const float*)d_in[5];
    const float* bn_beta  = (const float*)d_in[6];
    const float* bn_mean  = (const float*)d_in[7];
    const float* bn_var   = (const float*)d_in[8];
    const float* wih0     = (const float*)d_in[9];
    const float* whh0     = (const float*)d_in[10];
    const float* bih0     = (const float*)d_in[11];
    const float* bhh0     = (const float*)d_in[12];
    const float* wih1     = (const float*)d_in[13];
    const float* whh1     = (const float*)d_in[14];
    const float* bih1     = (const float*)d_in[15];
    const float* bhh1     = (const float*)d_in[16];
    const float* attn_w1  = (const float*)d_in[17];
    const float* attn_b1  = (const float*)d_in[18];
    const float* attn_w2  = (const float*)d_in[19];
    const float* attn_b2  = (const float*)d_in[20];
    const float* fc1_w    = (const float*)d_in[21];
    const float* fc1_b    = (const float*)d_in[22];
    const float* fc2_w    = (const float*)d_in[23];
    const float* fc2_b    = (const float*)d_in[24];

    char* p = (char*)d_ws;
    auto alloc = [&](size_t bytes) {
        void* r = (void*)p;
        p += (bytes + 255) & ~(size_t)255;
        return r;
    };
    ushort* xb      = (ushort*)alloc((size_t)M_*FIN_*2);
    ushort* aggbuf  = (ushort*)alloc((size_t)M_*H_*2);
    ushort* hbA     = (ushort*)alloc((size_t)M_*H_*2);
    ushort* hbB     = (ushort*)alloc((size_t)M_*H_*2);
    int*   cnt     = (int*)  alloc((size_t)M_*4);
    float* dinv    = (float*)alloc((size_t)M_*4);
    int*   bsum    = (int*)  alloc((size_t)SCAN_NB*4);
    int*   bexcl   = (int*)  alloc((size_t)SCAN_NB*4);
    int*   csr_off = (int*)  alloc((size_t)(M_+1)*4);
    int*   csr_cur = (int*)  alloc((size_t)M_*4);
    int*   csr_src = (int*)  alloc((size_t)TE_*4);
    float* bn_sc   = (float*)alloc(384*4);
    float* bn_sh   = (float*)alloc(384*4);
    float* bias0   = (float*)alloc(1024*4);
    float* bias1   = (float*)alloc(1024*4);
    ushort* w0t    = (ushort*)alloc((size_t)128*16*2);
    ushort* w1t    = (ushort*)alloc((size_t)128*128*2);
    ushort* w2t    = (ushort*)alloc((size_t)128*128*2);
    float* whh0_t  = (float*)alloc((size_t)2*H_*512*4);
    float* whh1_t  = (float*)alloc((size_t)2*H_*512*4);
    float* wih0_t  = (float*)alloc((size_t)2*H_*512*4);
    float* wih1_t  = (float*)alloc((size_t)2*256*512*4);
    float* emb     = (float*)alloc((size_t)T_*B_*H_*4);
    float* pre     = (float*)alloc((size_t)2*T_*B_*512*4);
    float* out1    = (float*)alloc((size_t)T_*B_*256*4);
    float* out2v   = (float*)alloc((size_t)T_*B_*256*4);
    float* attn_av = (float*)alloc((size_t)B_*T_*4);
    float* wsv     = (float*)alloc((size_t)B_*256*4);

    // --- graph preprocessing (CSR by dst) ---
    hipMemsetAsync(cnt, 0, (size_t)M_*4, stream);
    hipMemsetAsync(csr_cur, 0, (size_t)M_*4, stream);
    count_edges_k<<<(TE_+255)/256, 256, 0, stream>>>(ei, cnt);
    dinv_k<<<(M_+255)/256, 256, 0, stream>>>(cnt, dinv);
    scan1_k<<<SCAN_NB, 256, 0, stream>>>(cnt, bsum);
    scan2_k<<<1, 1, 0, stream>>>(bsum, bexcl, csr_off);
    scan3_k<<<SCAN_NB, 256, 0, stream>>>(cnt, bexcl, csr_off);
    fill_k<<<(TE_+255)/256, 256, 0, stream>>>(ei, csr_off, csr_cur, csr_src);

    // --- weight prep ---
    prep_k<<<4, 256, 0, stream>>>(gcn_b, bn_gamma, bn_beta, bn_mean, bn_var,
                                  bn_sc, bn_sh, bih0, bhh0, bias0, bih1, bhh1, bias1);
    convx_k<<<(M_*FIN_/4 + 255)/256, 256, 0, stream>>>(x, xb);
    convw_k<<<(16*128 + 255)/256, 256, 0, stream>>>(gcn_w0, w0t, 16, 128);
    convw_k<<<(128*128 + 255)/256, 256, 0, stream>>>(gcn_w12, w1t, 128, 128);
    convw_k<<<(128*128 + 255)/256, 256, 0, stream>>>(gcn_w12 + 128*128, w2t, 128, 128);
    transpose_k<<<256, 256, 0, stream>>>(whh0, whh0_t, 512, 128, 2);
    transpose_k<<<256, 256, 0, stream>>>(whh1, whh1_t, 512, 128, 2);
    transpose_k<<<256, 256, 0, stream>>>(wih0, wih0_t, 512, 128, 2);
    transpose_k<<<256, 256, 0, stream>>>(wih1, wih1_t, 512, 256, 2);

    // --- GCN layer 0 ---
    gather16_k<<<M_/32, 256, 0, stream>>>(xb, aggbuf, csr_off, csr_src, dinv);
    mm_mfma_k<16, false><<<M_/64, 256, 0, stream>>>(aggbuf, w0t, hbA,
                                                    bn_sc + 0, bn_sh + 0, nullptr);
    // --- GCN layer 1 ---
    gather128_k<<<M_/8, 256, 0, stream>>>(hbA, aggbuf, csr_off, csr_src, dinv);
    mm_mfma_k<128, true><<<M_/64, 256, 0, stream>>>(aggbuf, w1t, hbB,
                                                    bn_sc + 128, bn_sh + 128, hbA);
    // --- GCN layer 2 ---
    gather128_k<<<M_/8, 256, 0, stream>>>(hbB, aggbuf, csr_off, csr_src, dinv);
    mm_mfma_k<128, true><<<M_/64, 256, 0, stream>>>(aggbuf, w2t, hbA,
                                                    bn_sc + 256, bn_sh + 256, hbB);

    // --- mean pool -> emb [T*B,128] ---
    meanpool_k<<<T_*B_, 128, 0, stream>>>(hbA, emb);

    // --- BiLSTM layer 0 ---
    for (int dir = 0; dir < 2; dir++) {
        mm_k<<<dim3((T_*B_)/32, 4), 256, 0, stream>>>(
            emb, wih0_t + (size_t)dir*H_*512, pre + (size_t)dir*T_*B_*512,
            T_*B_, 128, 512, bias0 + dir*512);
    }
    lstm_scan_k<<<2*(B_/BC_), 512, 0, stream>>>(pre, whh0_t, out1);

    // --- BiLSTM layer 1 ---
    for (int dir = 0; dir < 2; dir++) {
        mm_k<<<dim3((T_*B_)/32, 4), 256, 0, stream>>>(
            out1, wih1_t + (size_t)dir*256*512, pre + (size_t)dir*T_*B_*512,
            T_*B_, 256, 512, bias1 + dir*512);
    }
    lstm_scan_k<<<2*(B_/BC_), 512, 0, stream>>>(pre, whh1_t, out2v);

    // --- attention ---
    attn_a_k<<<T_*B_, 128, 0, stream>>>(out2v, attn_w1, attn_b1, attn_w2, attn_b2, attn_av);
    attn_pool_k<<<B_, 256, 0, stream>>>(out2v, attn_av, wsv);

    // --- head ---
    head_k<<<B_, 512, 0, stream>>>(wsv, fc1_w, fc1_b, fc2_w, fc2_b, (float*)d_out);
}

// Round 3
// 621.329 us; speedup vs baseline: 2.4366x; 1.5491x over previous
//
#include <hip/hip_runtime.h>

#define T_ 48
#define B_ 32
#define N_ 96
#define E_ 24576
#define BN_ (B_*N_)      // 3072
#define M_ (T_*BN_)      // 147456
#define FIN_ 16
#define H_ 128
#define C_ 500
#define TE_ (T_*E_)      // 1179648
#define EPS_ 1e-5f
#define SCAN_NB (M_/256) // 576

typedef __bf16 bf16x8 __attribute__((ext_vector_type(8)));
typedef float  f32x4  __attribute__((ext_vector_type(4)));

__device__ __forceinline__ float bf2f(ushort u) {
    union { unsigned int i; float f; } v;
    v.i = ((unsigned int)u) << 16;
    return v.f;
}
__device__ __forceinline__ float bits2f(unsigned int u) {
    union { unsigned int i; float f; } v;
    v.i = u;
    return v.f;
}
__device__ __forceinline__ ushort f2bf(float f) {
    union { float f; unsigned int i; } v;
    v.f = f;
    unsigned int u = v.i;
    unsigned int r = (u + 0x7fffu + ((u >> 16) & 1u)) >> 16;
    return (ushort)r;
}
__device__ __forceinline__ float sigm(float x) {
    return 1.f / (1.f + __expf(-x));
}
__device__ __forceinline__ float ftanh(float x) {
    x = fminf(15.f, fmaxf(-15.f, x));
    float e = __expf(2.f * x);
    return (e - 1.f) / (e + 1.f);
}

// ---------------- graph preprocessing ----------------

__global__ void count_edges_k(const int* __restrict__ ei, int* __restrict__ cnt) {
    int i = blockIdx.x * blockDim.x + threadIdx.x;
    if (i >= TE_) return;
    int t = i / E_, e = i % E_;
    int dst = ei[(t*2+1)*E_ + e] + t*BN_;
    atomicAdd(&cnt[dst], 1);
}

__global__ void dinv_k(const int* __restrict__ cnt, float* __restrict__ dinv) {
    int i = blockIdx.x * blockDim.x + threadIdx.x;
    if (i >= M_) return;
    float deg = (float)cnt[i] + 1.0f;   // +1 self loop
    dinv[i] = rsqrtf(deg);
}

__global__ void scan1_k(const int* __restrict__ cnt, int* __restrict__ bsum) {
    __shared__ int s[256];
    int i = blockIdx.x*256 + threadIdx.x;
    s[threadIdx.x] = cnt[i];
    __syncthreads();
    for (int d = 128; d > 0; d >>= 1) {
        if (threadIdx.x < d) s[threadIdx.x] += s[threadIdx.x + d];
        __syncthreads();
    }
    if (threadIdx.x == 0) bsum[blockIdx.x] = s[0];
}

__global__ void scan2_k(const int* __restrict__ bsum, int* __restrict__ bexcl,
                        int* __restrict__ csr_off) {
    int run = 0;
    for (int i = 0; i < SCAN_NB; i++) { bexcl[i] = run; run += bsum[i]; }
    csr_off[M_] = run;
}

__global__ void scan3_k(const int* __restrict__ cnt, const int* __restrict__ bexcl,
                        int* __restrict__ csr_off) {
    __shared__ int s[256];
    int i = blockIdx.x*256 + threadIdx.x;
    int v = cnt[i];
    s[threadIdx.x] = v;
    __syncthreads();
    for (int d = 1; d < 256; d <<= 1) {
        int add = (threadIdx.x >= d) ? s[threadIdx.x - d] : 0;
        __syncthreads();
        s[threadIdx.x] += add;
        __syncthreads();
    }
    csr_off[i] = bexcl[blockIdx.x] + s[threadIdx.x] - v;  // exclusive
}

__global__ void fill_k(const int* __restrict__ ei, const int* __restrict__ csr_off,
                       int* __restrict__ cur, int* __restrict__ csr_src) {
    int i = blockIdx.x * blockDim.x + threadIdx.x;
    if (i >= TE_) return;
    int t = i / E_, e = i % E_;
    int src = ei[(t*2+0)*E_ + e] + t*BN_;
    int dst = ei[(t*2+1)*E_ + e] + t*BN_;
    int pos = atomicAdd(&cur[dst], 1);
    csr_src[csr_off[dst] + pos] = src;
}

// ---------------- conversions / weight prep ----------------

__global__ void convx_k(const float* __restrict__ in, ushort* __restrict__ out) {
    int i = blockIdx.x * blockDim.x + threadIdx.x;   // one per 4 elems
    if (i >= M_*FIN_/4) return;
    float4 v = *(const float4*)&in[i*4];
    ushort4 o;
    o.x = f2bf(v.x); o.y = f2bf(v.y); o.z = f2bf(v.z); o.w = f2bf(v.w);
    *(ushort4*)&out[i*4] = o;
}

// in f32 [K,N] -> out bf16 col-major [N][K]
__global__ void convw_k(const float* __restrict__ in, ushort* __restrict__ out,
                        int K, int Nn) {
    int i = blockIdx.x * blockDim.x + threadIdx.x;
    if (i >= K*Nn) return;
    int k = i / Nn, c = i - k*Nn;
    out[c*K + k] = f2bf(in[i]);
}

// flat f32 -> bf16
__global__ void convwf_k(const float* __restrict__ in, ushort* __restrict__ out, int n) {
    for (int i = blockIdx.x * blockDim.x + threadIdx.x; i < n;
         i += gridDim.x * blockDim.x)
        out[i] = f2bf(in[i]);
}

__global__ void prep_k(const float* __restrict__ gcn_b, const float* __restrict__ gam,
                       const float* __restrict__ bet, const float* __restrict__ mu,
                       const float* __restrict__ var,
                       float* __restrict__ bn_sc, float* __restrict__ bn_sh,
                       const float* __restrict__ bih0, const float* __restrict__ bhh0,
                       float* __restrict__ bias0,
                       const float* __restrict__ bih1, const float* __restrict__ bhh1,
                       float* __restrict__ bias1) {
    int i = blockIdx.x * blockDim.x + threadIdx.x;
    if (i < 3*H_) {
        float sc = gam[i] * rsqrtf(var[i] + EPS_);
        bn_sc[i] = sc;
        bn_sh[i] = gcn_b[i]*sc + bet[i] - mu[i]*sc;
    }
    if (i < 2*512) {
        bias0[i] = bih0[i] + bhh0[i];
        bias1[i] = bih1[i] + bhh1[i];
    }
}

__global__ void transpose_k(const float* __restrict__ in, float* __restrict__ out,
                            int R, int Cc, int nb) {
    int total = nb * R * Cc;
    for (int i = blockIdx.x * blockDim.x + threadIdx.x; i < total;
         i += gridDim.x * blockDim.x) {
        int b = i / (R * Cc);
        int rem = i - b * R * Cc;
        int r = rem / Cc, c = rem - r * Cc;
        out[(long)b*R*Cc + (long)c*R + r] = in[i];
    }
}

// ---------------- bf16 gathers (XCD-chunk swizzled) ----------------

__global__ __launch_bounds__(256) void gather128_k(
    const ushort* __restrict__ h, ushort* __restrict__ out,
    const int* __restrict__ csr_off, const int* __restrict__ csr_src,
    const float* __restrict__ dinv)
{
    int nb = gridDim.x;                  // M/8, divisible by 8
    int chunk = nb >> 3;
    int bswz = (blockIdx.x & 7) * chunk + (blockIdx.x >> 3);
    int node = bswz * 8 + (threadIdx.x >> 5);
    int l = threadIdx.x & 31;            // f0 = l*4
    float dv = dinv[node];
    const ushort* hr = h + (long)node*128 + l*4;
    ushort4 sv = *(const ushort4*)hr;
    float s = dv * dv;
    float a0 = bf2f(sv.x)*s, a1 = bf2f(sv.y)*s, a2 = bf2f(sv.z)*s, a3 = bf2f(sv.w)*s;
    int e0 = csr_off[node], e1 = csr_off[node+1];
    for (int j = e0; j < e1; j++) {
        int sc = csr_src[j];
        float en = dinv[sc] * dv;
        ushort4 v = *(const ushort4*)(h + (long)sc*128 + l*4);
        a0 += bf2f(v.x)*en; a1 += bf2f(v.y)*en; a2 += bf2f(v.z)*en; a3 += bf2f(v.w)*en;
    }
    ushort4 o;
    o.x = f2bf(a0); o.y = f2bf(a1); o.z = f2bf(a2); o.w = f2bf(a3);
    *(ushort4*)(out + (long)node*128 + l*4) = o;
}

__global__ __launch_bounds__(256) void gather16_k(
    const ushort* __restrict__ h, ushort* __restrict__ out,
    const int* __restrict__ csr_off, const int* __restrict__ csr_src,
    const float* __restrict__ dinv)
{
    int nb = gridDim.x;                  // M/32
    int chunk = nb >> 3;
    int bswz = (blockIdx.x & 7) * chunk + (blockIdx.x >> 3);
    int node = bswz * 32 + (threadIdx.x >> 3);
    int l = threadIdx.x & 7;             // f0 = l*2
    float dv = dinv[node];
    ushort2 sv = *(const ushort2*)(h + (long)node*16 + l*2);
    float s = dv * dv;
    float a0 = bf2f(sv.x)*s, a1 = bf2f(sv.y)*s;
    int e0 = csr_off[node], e1 = csr_off[node+1];
    for (int j = e0; j < e1; j++) {
        int sc = csr_src[j];
        float en = dinv[sc] * dv;
        ushort2 v = *(const ushort2*)(h + (long)sc*16 + l*2);
        a0 += bf2f(v.x)*en; a1 += bf2f(v.y)*en;
    }
    ushort2 o;
    o.x = f2bf(a0); o.y = f2bf(a1);
    *(ushort2*)(out + (long)node*16 + l*2) = o;
}

// ---------------- MFMA GEMM: GCN layers (BN+ReLU+resid epilogue) ----------------
template<int K, bool HASRES>
__global__ __launch_bounds__(256) void mm_mfma_k(
    const ushort* __restrict__ A, const ushort* __restrict__ Wt,
    ushort* __restrict__ Cout,
    const float* __restrict__ bnsc, const float* __restrict__ bnsh,
    const ushort* __restrict__ resid)
{
    int tid = threadIdx.x;
    int w = tid >> 6, lane = tid & 63;
    int l16 = lane & 15, lh = lane >> 4;
    int row0 = blockIdx.x * 64 + w * 16;

    f32x4 acc[8];
    #pragma unroll
    for (int i = 0; i < 8; i++) acc[i] = (f32x4){0.f, 0.f, 0.f, 0.f};

    #pragma unroll
    for (int k0 = 0; k0 < K; k0 += 32) {
        int ka = k0 + lh*8;
        bf16x8 af;
        bool valid = (K >= 32) || (ka < K);
        if (valid) {
            af = *reinterpret_cast<const bf16x8*>(&A[(long)(row0 + l16)*K + ka]);
        } else {
            #pragma unroll
            for (int e = 0; e < 8; e++) af[e] = (__bf16)0.f;
        }
        #pragma unroll
        for (int ct = 0; ct < 8; ct++) {
            bf16x8 bfr;
            if (valid) {
                bfr = *reinterpret_cast<const bf16x8*>(&Wt[(long)(ct*16 + l16)*K + ka]);
            } else {
                #pragma unroll
                for (int e = 0; e < 8; e++) bfr[e] = (__bf16)0.f;
            }
            acc[ct] = __builtin_amdgcn_mfma_f32_16x16x32_bf16(af, bfr, acc[ct], 0, 0, 0);
        }
    }

    #pragma unroll
    for (int ct = 0; ct < 8; ct++) {
        int col = ct*16 + l16;
        float sc = bnsc[col], sh = bnsh[col];
        #pragma unroll
        for (int r = 0; r < 4; r++) {
            int row = row0 + lh*4 + r;
            float v = acc[ct][r] * sc + sh;
            v = fmaxf(v, 0.f);
            if (HASRES) v += bf2f(resid[(long)row*128 + col]);
            Cout[(long)row*128 + col] = f2bf(v);
        }
    }
}

// ---------------- MFMA GEMM: LSTM input projection (bias, f32 out, N=512) ----
// A [Mr,K] bf16; Wt [512][K] bf16 (wih natural layout); C [Mr,512] f32.
template<int K>
__global__ __launch_bounds__(256) void mm_pre_k(
    const ushort* __restrict__ A, const ushort* __restrict__ Wt,
    float* __restrict__ Cout, const float* __restrict__ bias)
{
    int tid = threadIdx.x;
    int w = tid >> 6, lane = tid & 63;
    int l16 = lane & 15, lh = lane >> 4;
    int row0 = blockIdx.x * 64 + w * 16;
    int c0 = blockIdx.y * 128;

    f32x4 acc[8];
    #pragma unroll
    for (int i = 0; i < 8; i++) acc[i] = (f32x4){0.f, 0.f, 0.f, 0.f};

    #pragma unroll
    for (int k0 = 0; k0 < K; k0 += 32) {
        int ka = k0 + lh*8;
        bf16x8 af = *reinterpret_cast<const bf16x8*>(&A[(long)(row0 + l16)*K + ka]);
        #pragma unroll
        for (int ct = 0; ct < 8; ct++) {
            bf16x8 bfr = *reinterpret_cast<const bf16x8*>(&Wt[(long)(c0 + ct*16 + l16)*K + ka]);
            acc[ct] = __builtin_amdgcn_mfma_f32_16x16x32_bf16(af, bfr, acc[ct], 0, 0, 0);
        }
    }

    #pragma unroll
    for (int ct = 0; ct < 8; ct++) {
        int col = c0 + ct*16 + l16;
        float bv = bias[col];
        #pragma unroll
        for (int r = 0; r < 4; r++) {
            int row = row0 + lh*4 + r;
            Cout[(long)row*512 + col] = acc[ct][r] + bv;
        }
    }
}

// ---------------- mean pool (bf16 in, bf16 out) ----------------

__global__ void meanpool_k(const ushort* __restrict__ h, ushort* __restrict__ embb) {
    int row = blockIdx.x;            // t*B + b
    int t = row / B_, b = row - t*B_;
    int hh = threadIdx.x;
    const ushort* base = h + ((long)t*BN_ + b*N_)*H_ + hh;
    float acc = 0.f;
    for (int n = 0; n < N_; n++) acc += bf2f(base[(long)n*H_]);
    embb[(long)row*H_ + hh] = f2bf(acc * (1.f / N_));
}

// ---------------- LSTM scan: whh persistent in registers ----------------
// grid = 2 dirs * 32 batch = 64 blocks, 512 threads (thread = one gate).
__global__ __launch_bounds__(512) void lstm_scan_k(
    const float* __restrict__ pre,    // [2][T*B][512]
    const float* __restrict__ whh_t,  // [2][128][512] f32 (k-major)
    float* __restrict__ out,          // [T*B][256] f32
    ushort* __restrict__ outb)        // [T*B][256] bf16
{
    int dir = blockIdx.x >> 5;
    int b   = blockIdx.x & 31;
    int g   = threadIdx.x;            // gate 0..511

    __shared__ float h_s[H_];
    __shared__ float gbuf[512];
    if (g < H_) h_s[g] = 0.f;
    float creg = 0.f;                 // owned by threads g<128

    // preload whh[:,g] into 64 packed-bf16 registers
    const float* whh = whh_t + (long)dir * H_ * 512;
    unsigned int wpk[64];
    #pragma unroll
    for (int q = 0; q < 64; q++) {
        float w0 = whh[(2*q)*512 + g];
        float w1 = whh[(2*q+1)*512 + g];
        wpk[q] = (unsigned int)f2bf(w0) | ((unsigned int)f2bf(w1) << 16);
    }
    const float* pred = pre + (long)dir * T_ * B_ * 512;
    __syncthreads();

    for (int st = 0; st < T_; st++) {
        int t = dir ? (T_ - 1 - st) : st;
        float pv = pred[((long)t*B_ + b)*512 + g];
        const float4* h4 = (const float4*)h_s;
        float a0 = 0.f, a1 = 0.f, a2 = 0.f, a3 = 0.f;
        #pragma unroll
        for (int j = 0; j < 32; j++) {
            float4 hv = h4[j];
            unsigned int p0 = wpk[2*j], p1 = wpk[2*j+1];
            a0 += hv.x * bits2f(p0 << 16);
            a1 += hv.y * bits2f(p0 & 0xffff0000u);
            a2 += hv.z * bits2f(p1 << 16);
            a3 += hv.w * bits2f(p1 & 0xffff0000u);
        }
        gbuf[g] = pv + (a0 + a1) + (a2 + a3);
        __syncthreads();
        if (g < H_) {
            float ig = sigm(gbuf[g]);
            float fg = sigm(gbuf[128 + g]);
            float gg = ftanh(gbuf[256 + g]);
            float og = sigm(gbuf[384 + g]);
            float c = fg * creg + ig * gg;
            float h = og * ftanh(c);
            creg = c;
            h_s[g] = h;
            long orow = ((long)t*B_ + b)*256 + dir*H_ + g;
            out[orow] = h;
            outb[orow] = f2bf(h);
        }
        __syncthreads();
    }
}

// ---------------- attention ----------------

__global__ __launch_bounds__(128) void attn_a_k(
    const float* __restrict__ out2, const float* __restrict__ w1,
    const float* __restrict__ b1, const float* __restrict__ w2,
    const float* __restrict__ b2v, float* __restrict__ a)
{
    int row = blockIdx.x;
    int j = threadIdx.x;
    const float* xr = out2 + (long)row * 256;
    float acc = b1[j];
    for (int k = 0; k < 256; k++) acc += xr[k] * w1[k*128 + j];
    float u = tanhf(acc) * w2[j];
    __shared__ float red[128];
    red[j] = u;
    __syncthreads();
    for (int d = 64; d > 0; d >>= 1) {
        if (j < d) red[j] += red[j + d];
        __syncthreads();
    }
    if (j == 0) {
        int t = row / B_, b = row - t*B_;
        a[b*T_ + t] = red[0] + b2v[0];
    }
}

__global__ __launch_bounds__(256) void attn_pool_k(
    const float* __restrict__ out2, const float* __restrict__ a,
    float* __restrict__ wsv)
{
    int b = blockIdx.x;
    __shared__ float w[T_];
    if (threadIdx.x == 0) {
        float m = -1e30f;
        for (int t = 0; t < T_; t++) m = fmaxf(m, a[b*T_ + t]);
        float s = 0.f;
        for (int t = 0; t < T_; t++) { float e = __expf(a[b*T_ + t] - m); w[t] = e; s += e; }
        float inv = 1.f / s;
        for (int t = 0; t < T_; t++) w[t] *= inv;
    }
    __syncthreads();
    int h2 = threadIdx.x;
    float acc = 0.f;
    for (int t = 0; t < T_; t++) acc += w[t] * out2[((long)t*B_ + b)*256 + h2];
    wsv[b*256 + h2] = acc;
}

// ---------------- FC head + log_softmax ----------------

__global__ __launch_bounds__(512) void head_k(
    const float* __restrict__ wsv, const float* __restrict__ w1,
    const float* __restrict__ b1, const float* __restrict__ w2,
    const float* __restrict__ b2, float* __restrict__ outp)
{
    int b = blockIdx.x;
    int tid = threadIdx.x;
    __shared__ float r[128];
    __shared__ float y[C_];
    __shared__ float red[512];
    if (tid < 128) {
        float acc = b1[tid];
        for (int k = 0; k < 256; k++) acc += wsv[b*256 + k] * w1[k*128 + tid];
        r[tid] = fmaxf(acc, 0.f);
    }
    __syncthreads();
    for (int c = tid; c < C_; c += 512) {
        float acc = b2[c];
        for (int k = 0; k < 128; k++) acc += r[k] * w2[k*C_ + c];
        y[c] = acc;
    }
    __syncthreads();
    float m = -1e30f;
    for (int c = tid; c < C_; c += 512) m = fmaxf(m, y[c]);
    red[tid] = m;
    __syncthreads();
    for (int d = 256; d > 0; d >>= 1) {
        if (tid < d) red[tid] = fmaxf(red[tid], red[tid + d]);
        __syncthreads();
    }
    m = red[0];
    __syncthreads();
    float s = 0.f;
    for (int c = tid; c < C_; c += 512) s += __expf(y[c] - m);
    red[tid] = s;
    __syncthreads();
    for (int d = 256; d > 0; d >>= 1) {
        if (tid < d) red[tid] += red[tid + d];
        __syncthreads();
    }
    float lse = m + logf(red[0]);
    for (int c = tid; c < C_; c += 512) outp[(long)b*C_ + c] = y[c] - lse;
}

// ---------------- launch ----------------

extern "C" void kernel_launch(void* const* d_in, const int* in_sizes, int n_in,
                              void* d_out, int out_size, void* d_ws, size_t ws_size,
                              hipStream_t stream) {
    const float* x        = (const float*)d_in[0];
    const int*   ei       = (const int*)d_in[1];
    const float* gcn_w0   = (const float*)d_in[2];
    const float* gcn_w12  = (const float*)d_in[3];
    const float* gcn_b    = (const float*)d_in[4];
    const float* bn_gamma = (const float*)d_in[5];
    const float* bn_beta  = (const float*)d_in[6];
    const float* bn_mean  = (const float*)d_in[7];
    const float* bn_var   = (const float*)d_in[8];
    const float* wih0     = (const float*)d_in[9];
    const float* whh0     = (const float*)d_in[10];
    const float* bih0     = (const float*)d_in[11];
    const float* bhh0     = (const float*)d_in[12];
    const float* wih1     = (const float*)d_in[13];
    const float* whh1     = (const float*)d_in[14];
    const float* bih1     = (const float*)d_in[15];
    const float* bhh1     = (const float*)d_in[16];
    const float* attn_w1  = (const float*)d_in[17];
    const float* attn_b1  = (const float*)d_in[18];
    const float* attn_w2  = (const float*)d_in[19];
    const float* attn_b2  = (const float*)d_in[20];
    const float* fc1_w    = (const float*)d_in[21];
    const float* fc1_b    = (const float*)d_in[22];
    const float* fc2_w    = (const float*)d_in[23];
    const float* fc2_b    = (const float*)d_in[24];

    char* p = (char*)d_ws;
    auto alloc = [&](size_t bytes) {
        void* r = (void*)p;
        p += (bytes + 255) & ~(size_t)255;
        return r;
    };
    ushort* xb     = (ushort*)alloc((size_t)M_*FIN_*2);
    ushort* aggbuf = (ushort*)alloc((size_t)M_*H_*2);
    ushort* hbA    = (ushort*)alloc((size_t)M_*H_*2);
    ushort* hbB    = (ushort*)alloc((size_t)M_*H_*2);
    int*   cnt     = (int*)  alloc((size_t)M_*4);
    float* dinv    = (float*)alloc((size_t)M_*4);
    int*   bsum    = (int*)  alloc((size_t)SCAN_NB*4);
    int*   bexcl   = (int*)  alloc((size_t)SCAN_NB*4);
    int*   csr_off = (int*)  alloc((size_t)(M_+1)*4);
    int*   csr_cur = (int*)  alloc((size_t)M_*4);
    int*   csr_src = (int*)  alloc((size_t)TE_*4);
    float* bn_sc   = (float*)alloc(384*4);
    float* bn_sh   = (float*)alloc(384*4);
    float* bias0   = (float*)alloc(1024*4);
    float* bias1   = (float*)alloc(1024*4);
    ushort* w0t    = (ushort*)alloc((size_t)128*16*2);
    ushort* w1t    = (ushort*)alloc((size_t)128*128*2);
    ushort* w2t    = (ushort*)alloc((size_t)128*128*2);
    float* whh0_t  = (float*)alloc((size_t)2*H_*512*4);
    float* whh1_t  = (float*)alloc((size_t)2*H_*512*4);
    ushort* wih0b  = (ushort*)alloc((size_t)2*512*128*2);
    ushort* wih1b  = (ushort*)alloc((size_t)2*512*256*2);
    ushort* embb   = (ushort*)alloc((size_t)T_*B_*H_*2);
    float* pre     = (float*)alloc((size_t)2*T_*B_*512*4);
    float* out1    = (float*)alloc((size_t)T_*B_*256*4);
    ushort* out1b  = (ushort*)alloc((size_t)T_*B_*256*2);
    float* out2v   = (float*)alloc((size_t)T_*B_*256*4);
    ushort* out2b  = (ushort*)alloc((size_t)T_*B_*256*2);
    float* attn_av = (float*)alloc((size_t)B_*T_*4);
    float* wsv     = (float*)alloc((size_t)B_*256*4);

    // --- graph preprocessing (CSR by dst) ---
    hipMemsetAsync(cnt, 0, (size_t)M_*4, stream);
    hipMemsetAsync(csr_cur, 0, (size_t)M_*4, stream);
    count_edges_k<<<(TE_+255)/256, 256, 0, stream>>>(ei, cnt);
    dinv_k<<<(M_+255)/256, 256, 0, stream>>>(cnt, dinv);
    scan1_k<<<SCAN_NB, 256, 0, stream>>>(cnt, bsum);
    scan2_k<<<1, 1, 0, stream>>>(bsum, bexcl, csr_off);
    scan3_k<<<SCAN_NB, 256, 0, stream>>>(cnt, bexcl, csr_off);
    fill_k<<<(TE_+255)/256, 256, 0, stream>>>(ei, csr_off, csr_cur, csr_src);

    // --- weight prep ---
    prep_k<<<4, 256, 0, stream>>>(gcn_b, bn_gamma, bn_beta, bn_mean, bn_var,
                                  bn_sc, bn_sh, bih0, bhh0, bias0, bih1, bhh1, bias1);
    convx_k<<<(M_*FIN_/4 + 255)/256, 256, 0, stream>>>(x, xb);
    convw_k<<<(16*128 + 255)/256, 256, 0, stream>>>(gcn_w0, w0t, 16, 128);
    convw_k<<<(128*128 + 255)/256, 256, 0, stream>>>(gcn_w12, w1t, 128, 128);
    convw_k<<<(128*128 + 255)/256, 256, 0, stream>>>(gcn_w12 + 128*128, w2t, 128, 128);
    transpose_k<<<256, 256, 0, stream>>>(whh0, whh0_t, 512, 128, 2);
    transpose_k<<<256, 256, 0, stream>>>(whh1, whh1_t, 512, 128, 2);
    convwf_k<<<128, 256, 0, stream>>>(wih0, wih0b, 2*512*128);
    convwf_k<<<256, 256, 0, stream>>>(wih1, wih1b, 2*512*256);

    // --- GCN layer 0 ---
    gather16_k<<<M_/32, 256, 0, stream>>>(xb, aggbuf, csr_off, csr_src, dinv);
    mm_mfma_k<16, false><<<M_/64, 256, 0, stream>>>(aggbuf, w0t, hbA,
                                                    bn_sc + 0, bn_sh + 0, nullptr);
    // --- GCN layer 1 ---
    gather128_k<<<M_/8, 256, 0, stream>>>(hbA, aggbuf, csr_off, csr_src, dinv);
    mm_mfma_k<128, true><<<M_/64, 256, 0, stream>>>(aggbuf, w1t, hbB,
                                                    bn_sc + 128, bn_sh + 128, hbA);
    // --- GCN layer 2 ---
    gather128_k<<<M_/8, 256, 0, stream>>>(hbB, aggbuf, csr_off, csr_src, dinv);
    mm_mfma_k<128, true><<<M_/64, 256, 0, stream>>>(aggbuf, w2t, hbA,
                                                    bn_sc + 256, bn_sh + 256, hbB);

    // --- mean pool -> embb [T*B,128] bf16 ---
    meanpool_k<<<T_*B_, 128, 0, stream>>>(hbA, embb);

    // --- BiLSTM layer 0 ---
    for (int dir = 0; dir < 2; dir++) {
        mm_pre_k<128><<<dim3((T_*B_)/64, 4), 256, 0, stream>>>(
            embb, wih0b + (size_t)dir*512*128, pre + (size_t)dir*T_*B_*512,
            bias0 + dir*512);
    }
    lstm_scan_k<<<64, 512, 0, stream>>>(pre, whh0_t, out1, out1b);

    // --- BiLSTM layer 1 ---
    for (int dir = 0; dir < 2; dir++) {
        mm_pre_k<256><<<dim3((T_*B_)/64, 4), 256, 0, stream>>>(
            out1b, wih1b + (size_t)dir*512*256, pre + (size_t)dir*T_*B_*512,
            bias1 + dir*512);
    }
    lstm_scan_k<<<64, 512, 0, stream>>>(pre, whh1_t, out2v, out2b);

    // --- attention ---
    attn_a_k<<<T_*B_, 128, 0, stream>>>(out2v, attn_w1, attn_b1, attn_w2, attn_b2, attn_av);
    attn_pool_k<<<B_, 256, 0, stream>>>(out2v, attn_av, wsv);

    // --- head ---
    head_k<<<B_, 512, 0, stream>>>(wsv, fc1_w, fc1_b, fc2_w, fc2_b, (float*)d_out);
}

// Round 4
// 540.174 us; speedup vs baseline: 2.8027x; 1.1502x over previous
//
#include <hip/hip_runtime.h>

#define T_ 48
#define B_ 32
#define N_ 96
#define E_ 24576
#define BN_ (B_*N_)      // 3072
#define M_ (T_*BN_)      // 147456
#define FIN_ 16
#define H_ 128
#define C_ 500
#define TE_ (T_*E_)      // 1179648
#define EPS_ 1e-5f
#define SCAN_NB (M_/256) // 576

typedef __bf16 bf16x8 __attribute__((ext_vector_type(8)));
typedef float  f32x4  __attribute__((ext_vector_type(4)));

__device__ __forceinline__ float bf2f(ushort u) {
    union { unsigned int i; float f; } v;
    v.i = ((unsigned int)u) << 16;
    return v.f;
}
__device__ __forceinline__ float bits2f(unsigned int u) {
    union { unsigned int i; float f; } v;
    v.i = u;
    return v.f;
}
__device__ __forceinline__ ushort f2bf(float f) {
    union { float f; unsigned int i; } v;
    v.f = f;
    unsigned int u = v.i;
    unsigned int r = (u + 0x7fffu + ((u >> 16) & 1u)) >> 16;
    return (ushort)r;
}
__device__ __forceinline__ float sigm(float x) {
    return 1.f / (1.f + __expf(-x));
}
__device__ __forceinline__ float ftanh(float x) {
    x = fminf(15.f, fmaxf(-15.f, x));
    float e = __expf(2.f * x);
    return (e - 1.f) / (e + 1.f);
}

// ---------------- graph preprocessing ----------------

__global__ void count_edges_k(const int* __restrict__ ei, int* __restrict__ cnt) {
    int i = blockIdx.x * blockDim.x + threadIdx.x;
    if (i >= TE_) return;
    int t = i / E_, e = i % E_;
    int dst = ei[(t*2+1)*E_ + e] + t*BN_;
    atomicAdd(&cnt[dst], 1);
}

// block reduction of cnt + dinv computation
__global__ void scan1_k(const int* __restrict__ cnt, int* __restrict__ bsum,
                        float* __restrict__ dinv) {
    __shared__ int s[256];
    int i = blockIdx.x*256 + threadIdx.x;
    int v = cnt[i];
    dinv[i] = rsqrtf((float)v + 1.0f);
    s[threadIdx.x] = v;
    __syncthreads();
    for (int d = 128; d > 0; d >>= 1) {
        if (threadIdx.x < d) s[threadIdx.x] += s[threadIdx.x + d];
        __syncthreads();
    }
    if (threadIdx.x == 0) bsum[blockIdx.x] = s[0];
}

// parallel single-block scan over SCAN_NB block sums
__global__ __launch_bounds__(256) void scan2_k(const int* __restrict__ bsum,
                                               int* __restrict__ bexcl,
                                               int* __restrict__ csr_off) {
    __shared__ int part[256];
    int tid = threadIdx.x;
    int base = tid*3;   // 256*3 = 768 >= 576
    int a = (base   < SCAN_NB) ? bsum[base]   : 0;
    int b = (base+1 < SCAN_NB) ? bsum[base+1] : 0;
    int c = (base+2 < SCAN_NB) ? bsum[base+2] : 0;
    int tot = a + b + c;
    part[tid] = tot;
    __syncthreads();
    for (int d = 1; d < 256; d <<= 1) {
        int add = (tid >= d) ? part[tid - d] : 0;
        __syncthreads();
        part[tid] += add;
        __syncthreads();
    }
    int excl = part[tid] - tot;
    if (base   < SCAN_NB) bexcl[base]   = excl;
    if (base+1 < SCAN_NB) bexcl[base+1] = excl + a;
    if (base+2 < SCAN_NB) bexcl[base+2] = excl + a + b;
    if (tid == 255) csr_off[M_] = part[255];
}

__global__ void scan3_k(const int* __restrict__ cnt, const int* __restrict__ bexcl,
                        int* __restrict__ csr_off) {
    __shared__ int s[256];
    int i = blockIdx.x*256 + threadIdx.x;
    int v = cnt[i];
    s[threadIdx.x] = v;
    __syncthreads();
    for (int d = 1; d < 256; d <<= 1) {
        int add = (threadIdx.x >= d) ? s[threadIdx.x - d] : 0;
        __syncthreads();
        s[threadIdx.x] += add;
        __syncthreads();
    }
    csr_off[i] = bexcl[blockIdx.x] + s[threadIdx.x] - v;  // exclusive
}

__global__ void fill_k(const int* __restrict__ ei, const int* __restrict__ csr_off,
                       int* __restrict__ cur, int* __restrict__ csr_src) {
    int i = blockIdx.x * blockDim.x + threadIdx.x;
    if (i >= TE_) return;
    int t = i / E_, e = i % E_;
    int src = ei[(t*2+0)*E_ + e] + t*BN_;
    int dst = ei[(t*2+1)*E_ + e] + t*BN_;
    int pos = atomicAdd(&cur[dst], 1);
    csr_src[csr_off[dst] + pos] = src;
}

// ---------------- conversions / merged weight prep ----------------

__global__ void convx_k(const float* __restrict__ in, ushort* __restrict__ out) {
    int i = blockIdx.x * blockDim.x + threadIdx.x;   // one per 4 elems
    if (i >= M_*FIN_/4) return;
    float4 v = *(const float4*)&in[i*4];
    ushort4 o;
    o.x = f2bf(v.x); o.y = f2bf(v.y); o.z = f2bf(v.z); o.w = f2bf(v.w);
    *(ushort4*)&out[i*4] = o;
}

// one kernel for all small weight preparation
// segments (running offset):
//  [0,384)        bn scale/shift
//  [+1024)        lstm bias0/bias1 (both)
//  [+2048)        w0t  (gcn_w0 [16,128] -> [128][16])
//  [+16384)       w1t  (gcn_w12[0] -> [128][128] col-major)
//  [+16384)       w2t  (gcn_w12[1])
//  [+65536)       wpk0 (whh0 packed bf16 pairs [2][64][512])
//  [+65536)       wpk1
//  [+131072)      wih0b flat bf16
//  [+262144)      wih1b flat bf16
#define WPREP_TOTAL (384+1024+2048+16384+16384+65536+65536+131072+262144)
__global__ void wprep_k(
    const float* __restrict__ gcn_b, const float* __restrict__ gam,
    const float* __restrict__ bet, const float* __restrict__ mu,
    const float* __restrict__ var,
    float* __restrict__ bn_sc, float* __restrict__ bn_sh,
    const float* __restrict__ bih0, const float* __restrict__ bhh0,
    float* __restrict__ bias0,
    const float* __restrict__ bih1, const float* __restrict__ bhh1,
    float* __restrict__ bias1,
    const float* __restrict__ gcn_w0, const float* __restrict__ gcn_w12,
    ushort* __restrict__ w0t, ushort* __restrict__ w1t, ushort* __restrict__ w2t,
    const float* __restrict__ whh0, const float* __restrict__ whh1,
    unsigned int* __restrict__ wpk0, unsigned int* __restrict__ wpk1,
    const float* __restrict__ wih0, const float* __restrict__ wih1,
    ushort* __restrict__ wih0b, ushort* __restrict__ wih1b)
{
    int i = blockIdx.x * blockDim.x + threadIdx.x;
    if (i >= WPREP_TOTAL) return;
    if (i < 384) {
        float sc = gam[i] * rsqrtf(var[i] + EPS_);
        bn_sc[i] = sc;
        bn_sh[i] = gcn_b[i]*sc + bet[i] - mu[i]*sc;
        return;
    }
    i -= 384;
    if (i < 1024) {
        bias0[i] = bih0[i] + bhh0[i];
        bias1[i] = bih1[i] + bhh1[i];
        return;
    }
    i -= 1024;
    if (i < 2048) {
        int k = i >> 7, c = i & 127;
        w0t[c*16 + k] = f2bf(gcn_w0[i]);
        return;
    }
    i -= 2048;
    if (i < 16384) {
        int k = i >> 7, c = i & 127;
        w1t[c*128 + k] = f2bf(gcn_w12[i]);
        return;
    }
    i -= 16384;
    if (i < 16384) {
        int k = i >> 7, c = i & 127;
        w2t[c*128 + k] = f2bf(gcn_w12[16384 + i]);
        return;
    }
    i -= 16384;
    if (i < 65536) {
        // i = (dir*64 + q)*512 + g
        int g = i & 511;
        int qd = i >> 9;
        int dir = qd >> 6, q = qd & 63;
        const float* wr = whh0 + ((long)(dir*512 + g))*128 + 2*q;
        wpk0[i] = (unsigned int)f2bf(wr[0]) | ((unsigned int)f2bf(wr[1]) << 16);
        return;
    }
    i -= 65536;
    if (i < 65536) {
        int g = i & 511;
        int qd = i >> 9;
        int dir = qd >> 6, q = qd & 63;
        const float* wr = whh1 + ((long)(dir*512 + g))*128 + 2*q;
        wpk1[i] = (unsigned int)f2bf(wr[0]) | ((unsigned int)f2bf(wr[1]) << 16);
        return;
    }
    i -= 65536;
    if (i < 131072) {
        wih0b[i] = f2bf(wih0[i]);
        return;
    }
    i -= 131072;
    wih1b[i] = f2bf(wih1[i]);
}

// ---------------- bf16 gathers (XCD-chunk swizzled, ILP-unrolled) ----------------

// F=128 split into 2 passes of 64 feats (blockIdx.y); 16 nodes/block, 16 lanes/node.
__global__ __launch_bounds__(256) void gather128_k(
    const ushort* __restrict__ h, ushort* __restrict__ out,
    const int* __restrict__ csr_off, const int* __restrict__ csr_src,
    const float* __restrict__ dinv)
{
    int nb = gridDim.x;                  // M/16, divisible by 8
    int chunk = nb >> 3;
    int bswz = (blockIdx.x & 7) * chunk + (blockIdx.x >> 3);
    int node = bswz * 16 + (threadIdx.x >> 4);
    int f0 = blockIdx.y * 64 + (threadIdx.x & 15) * 4;
    float dv = dinv[node];
    ushort4 sv = *(const ushort4*)(h + (long)node*128 + f0);
    float s = dv * dv;
    float a0 = bf2f(sv.x)*s, a1 = bf2f(sv.y)*s, a2 = bf2f(sv.z)*s, a3 = bf2f(sv.w)*s;
    int e0 = csr_off[node], e1 = csr_off[node+1];
    int j = e0;
    for (; j + 4 <= e1; j += 4) {
        int s0 = csr_src[j], s1 = csr_src[j+1], s2 = csr_src[j+2], s3 = csr_src[j+3];
        float d0 = dinv[s0], d1 = dinv[s1], d2 = dinv[s2], d3 = dinv[s3];
        ushort4 v0 = *(const ushort4*)(h + (long)s0*128 + f0);
        ushort4 v1 = *(const ushort4*)(h + (long)s1*128 + f0);
        ushort4 v2 = *(const ushort4*)(h + (long)s2*128 + f0);
        ushort4 v3 = *(const ushort4*)(h + (long)s3*128 + f0);
        d0 *= dv; d1 *= dv; d2 *= dv; d3 *= dv;
        a0 += bf2f(v0.x)*d0 + bf2f(v1.x)*d1 + bf2f(v2.x)*d2 + bf2f(v3.x)*d3;
        a1 += bf2f(v0.y)*d0 + bf2f(v1.y)*d1 + bf2f(v2.y)*d2 + bf2f(v3.y)*d3;
        a2 += bf2f(v0.z)*d0 + bf2f(v1.z)*d1 + bf2f(v2.z)*d2 + bf2f(v3.z)*d3;
        a3 += bf2f(v0.w)*d0 + bf2f(v1.w)*d1 + bf2f(v2.w)*d2 + bf2f(v3.w)*d3;
    }
    for (; j < e1; j++) {
        int sc = csr_src[j];
        float en = dinv[sc] * dv;
        ushort4 v = *(const ushort4*)(h + (long)sc*128 + f0);
        a0 += bf2f(v.x)*en; a1 += bf2f(v.y)*en; a2 += bf2f(v.z)*en; a3 += bf2f(v.w)*en;
    }
    ushort4 o;
    o.x = f2bf(a0); o.y = f2bf(a1); o.z = f2bf(a2); o.w = f2bf(a3);
    *(ushort4*)(out + (long)node*128 + f0) = o;
}

// F=16: 32 nodes/block, 8 lanes/node, ushort2 per lane, unrolled x4
__global__ __launch_bounds__(256) void gather16_k(
    const ushort* __restrict__ h, ushort* __restrict__ out,
    const int* __restrict__ csr_off, const int* __restrict__ csr_src,
    const float* __restrict__ dinv)
{
    int nb = gridDim.x;                  // M/32
    int chunk = nb >> 3;
    int bswz = (blockIdx.x & 7) * chunk + (blockIdx.x >> 3);
    int node = bswz * 32 + (threadIdx.x >> 3);
    int f0 = (threadIdx.x & 7) * 2;
    float dv = dinv[node];
    ushort2 sv = *(const ushort2*)(h + (long)node*16 + f0);
    float s = dv * dv;
    float a0 = bf2f(sv.x)*s, a1 = bf2f(sv.y)*s;
    int e0 = csr_off[node], e1 = csr_off[node+1];
    int j = e0;
    for (; j + 4 <= e1; j += 4) {
        int s0 = csr_src[j], s1 = csr_src[j+1], s2 = csr_src[j+2], s3 = csr_src[j+3];
        float d0 = dinv[s0], d1 = dinv[s1], d2 = dinv[s2], d3 = dinv[s3];
        ushort2 v0 = *(const ushort2*)(h + (long)s0*16 + f0);
        ushort2 v1 = *(const ushort2*)(h + (long)s1*16 + f0);
        ushort2 v2 = *(const ushort2*)(h + (long)s2*16 + f0);
        ushort2 v3 = *(const ushort2*)(h + (long)s3*16 + f0);
        d0 *= dv; d1 *= dv; d2 *= dv; d3 *= dv;
        a0 += bf2f(v0.x)*d0 + bf2f(v1.x)*d1 + bf2f(v2.x)*d2 + bf2f(v3.x)*d3;
        a1 += bf2f(v0.y)*d0 + bf2f(v1.y)*d1 + bf2f(v2.y)*d2 + bf2f(v3.y)*d3;
    }
    for (; j < e1; j++) {
        int sc = csr_src[j];
        float en = dinv[sc] * dv;
        ushort2 v = *(const ushort2*)(h + (long)sc*16 + f0);
        a0 += bf2f(v.x)*en; a1 += bf2f(v.y)*en;
    }
    ushort2 o;
    o.x = f2bf(a0); o.y = f2bf(a1);
    *(ushort2*)(out + (long)node*16 + f0) = o;
}

// ---------------- MFMA GEMM: GCN layers (BN+ReLU+resid epilogue) ----------------
template<int K, bool HASRES>
__global__ __launch_bounds__(256) void mm_mfma_k(
    const ushort* __restrict__ A, const ushort* __restrict__ Wt,
    ushort* __restrict__ Cout,
    const float* __restrict__ bnsc, const float* __restrict__ bnsh,
    const ushort* __restrict__ resid)
{
    int tid = threadIdx.x;
    int w = tid >> 6, lane = tid & 63;
    int l16 = lane & 15, lh = lane >> 4;
    int row0 = blockIdx.x * 64 + w * 16;

    f32x4 acc[8];
    #pragma unroll
    for (int i = 0; i < 8; i++) acc[i] = (f32x4){0.f, 0.f, 0.f, 0.f};

    #pragma unroll
    for (int k0 = 0; k0 < K; k0 += 32) {
        int ka = k0 + lh*8;
        bf16x8 af;
        bool valid = (K >= 32) || (ka < K);
        if (valid) {
            af = *reinterpret_cast<const bf16x8*>(&A[(long)(row0 + l16)*K + ka]);
        } else {
            #pragma unroll
            for (int e = 0; e < 8; e++) af[e] = (__bf16)0.f;
        }
        #pragma unroll
        for (int ct = 0; ct < 8; ct++) {
            bf16x8 bfr;
            if (valid) {
                bfr = *reinterpret_cast<const bf16x8*>(&Wt[(long)(ct*16 + l16)*K + ka]);
            } else {
                #pragma unroll
                for (int e = 0; e < 8; e++) bfr[e] = (__bf16)0.f;
            }
            acc[ct] = __builtin_amdgcn_mfma_f32_16x16x32_bf16(af, bfr, acc[ct], 0, 0, 0);
        }
    }

    #pragma unroll
    for (int ct = 0; ct < 8; ct++) {
        int col = ct*16 + l16;
        float sc = bnsc[col], sh = bnsh[col];
        #pragma unroll
        for (int r = 0; r < 4; r++) {
            int row = row0 + lh*4 + r;
            float v = acc[ct][r] * sc + sh;
            v = fmaxf(v, 0.f);
            if (HASRES) v += bf2f(resid[(long)row*128 + col]);
            Cout[(long)row*128 + col] = f2bf(v);
        }
    }
}

// ---------------- MFMA GEMM: LSTM input projection (both dirs via blockIdx.z) ----
template<int K>
__global__ __launch_bounds__(256) void mm_pre_k(
    const ushort* __restrict__ A, const ushort* __restrict__ Wt_all,
    float* __restrict__ Cout_all, const float* __restrict__ bias_all)
{
    int dir = blockIdx.z;
    const ushort* Wt = Wt_all + (size_t)dir * 512 * K;
    float* Cout = Cout_all + (size_t)dir * T_ * B_ * 512;
    const float* bias = bias_all + dir * 512;

    int tid = threadIdx.x;
    int w = tid >> 6, lane = tid & 63;
    int l16 = lane & 15, lh = lane >> 4;
    int row0 = blockIdx.x * 64 + w * 16;
    int c0 = blockIdx.y * 128;

    f32x4 acc[8];
    #pragma unroll
    for (int i = 0; i < 8; i++) acc[i] = (f32x4){0.f, 0.f, 0.f, 0.f};

    #pragma unroll
    for (int k0 = 0; k0 < K; k0 += 32) {
        int ka = k0 + lh*8;
        bf16x8 af = *reinterpret_cast<const bf16x8*>(&A[(long)(row0 + l16)*K + ka]);
        #pragma unroll
        for (int ct = 0; ct < 8; ct++) {
            bf16x8 bfr = *reinterpret_cast<const bf16x8*>(&Wt[(long)(c0 + ct*16 + l16)*K + ka]);
            acc[ct] = __builtin_amdgcn_mfma_f32_16x16x32_bf16(af, bfr, acc[ct], 0, 0, 0);
        }
    }

    #pragma unroll
    for (int ct = 0; ct < 8; ct++) {
        int col = c0 + ct*16 + l16;
        float bv = bias[col];
        #pragma unroll
        for (int r = 0; r < 4; r++) {
            int row = row0 + lh*4 + r;
            Cout[(long)row*512 + col] = acc[ct][r] + bv;
        }
    }
}

// ---------------- mean pool (bf16 in, bf16 out) ----------------

__global__ void meanpool_k(const ushort* __restrict__ h, ushort* __restrict__ embb) {
    int row = blockIdx.x;            // t*B + b
    int t = row / B_, b = row - t*B_;
    int hh = threadIdx.x;
    const ushort* base = h + ((long)t*BN_ + b*N_)*H_ + hh;
    float acc = 0.f;
    for (int n = 0; n < N_; n++) acc += bf2f(base[(long)n*H_]);
    embb[(long)row*H_ + hh] = f2bf(acc * (1.f / N_));
}

// ---------------- LSTM scan: whh persistent in registers ----------------
// grid = 2 dirs * 32 batch = 64 blocks, 512 threads (thread = one gate).
__global__ __launch_bounds__(512) void lstm_scan_k(
    const float* __restrict__ pre,    // [2][T*B][512]
    const unsigned int* __restrict__ wpkbuf, // [2][64][512] packed bf16 pairs
    float* __restrict__ out,          // [T*B][256] f32
    ushort* __restrict__ outb)        // [T*B][256] bf16
{
    int dir = blockIdx.x >> 5;
    int b   = blockIdx.x & 31;
    int g   = threadIdx.x;            // gate 0..511

    __shared__ float h_s[H_];
    __shared__ float gbuf[512];
    if (g < H_) h_s[g] = 0.f;
    float creg = 0.f;                 // owned by threads g<128

    const unsigned int* wp = wpkbuf + (long)dir * 64 * 512;
    unsigned int wpk[64];
    #pragma unroll
    for (int q = 0; q < 64; q++) wpk[q] = wp[q*512 + g];

    const float* pred = pre + (long)dir * T_ * B_ * 512;
    __syncthreads();

    for (int st = 0; st < T_; st++) {
        int t = dir ? (T_ - 1 - st) : st;
        float pv = pred[((long)t*B_ + b)*512 + g];
        const float4* h4 = (const float4*)h_s;
        float a0 = 0.f, a1 = 0.f, a2 = 0.f, a3 = 0.f;
        #pragma unroll
        for (int j = 0; j < 32; j++) {
            float4 hv = h4[j];
            unsigned int p0 = wpk[2*j], p1 = wpk[2*j+1];
            a0 += hv.x * bits2f(p0 << 16);
            a1 += hv.y * bits2f(p0 & 0xffff0000u);
            a2 += hv.z * bits2f(p1 << 16);
            a3 += hv.w * bits2f(p1 & 0xffff0000u);
        }
        gbuf[g] = pv + (a0 + a1) + (a2 + a3);
        __syncthreads();
        if (g < H_) {
            float ig = sigm(gbuf[g]);
            float fg = sigm(gbuf[128 + g]);
            float gg = ftanh(gbuf[256 + g]);
            float og = sigm(gbuf[384 + g]);
            float c = fg * creg + ig * gg;
            float h = og * ftanh(c);
            creg = c;
            h_s[g] = h;
            long orow = ((long)t*B_ + b)*256 + dir*H_ + g;
            out[orow] = h;
            outb[orow] = f2bf(h);
        }
        __syncthreads();
    }
}

// ---------------- attention ----------------

__global__ __launch_bounds__(128) void attn_a_k(
    const float* __restrict__ out2, const float* __restrict__ w1,
    const float* __restrict__ b1, const float* __restrict__ w2,
    const float* __restrict__ b2v, float* __restrict__ a)
{
    int row = blockIdx.x;
    int j = threadIdx.x;
    const float* xr = out2 + (long)row * 256;
    float acc = b1[j];
    for (int k = 0; k < 256; k++) acc += xr[k] * w1[k*128 + j];
    float u = tanhf(acc) * w2[j];
    __shared__ float red[128];
    red[j] = u;
    __syncthreads();
    for (int d = 64; d > 0; d >>= 1) {
        if (j < d) red[j] += red[j + d];
        __syncthreads();
    }
    if (j == 0) {
        int t = row / B_, b = row - t*B_;
        a[b*T_ + t] = red[0] + b2v[0];
    }
}

__global__ __launch_bounds__(256) void attn_pool_k(
    const float* __restrict__ out2, const float* __restrict__ a,
    float* __restrict__ wsv)
{
    int b = blockIdx.x;
    __shared__ float w[T_];
    if (threadIdx.x == 0) {
        float m = -1e30f;
        for (int t = 0; t < T_; t++) m = fmaxf(m, a[b*T_ + t]);
        float s = 0.f;
        for (int t = 0; t < T_; t++) { float e = __expf(a[b*T_ + t] - m); w[t] = e; s += e; }
        float inv = 1.f / s;
        for (int t = 0; t < T_; t++) w[t] *= inv;
    }
    __syncthreads();
    int h2 = threadIdx.x;
    float acc = 0.f;
    for (int t = 0; t < T_; t++) acc += w[t] * out2[((long)t*B_ + b)*256 + h2];
    wsv[b*256 + h2] = acc;
}

// ---------------- FC head + log_softmax ----------------

__global__ __launch_bounds__(512) void head_k(
    const float* __restrict__ wsv, const float* __restrict__ w1,
    const float* __restrict__ b1, const float* __restrict__ w2,
    const float* __restrict__ b2, float* __restrict__ outp)
{
    int b = blockIdx.x;
    int tid = threadIdx.x;
    __shared__ float r[128];
    __shared__ float y[C_];
    __shared__ float red[512];
    if (tid < 128) {
        float acc = b1[tid];
        for (int k = 0; k < 256; k++) acc += wsv[b*256 + k] * w1[k*128 + tid];
        r[tid] = fmaxf(acc, 0.f);
    }
    __syncthreads();
    for (int c = tid; c < C_; c += 512) {
        float acc = b2[c];
        for (int k = 0; k < 128; k++) acc += r[k] * w2[k*C_ + c];
        y[c] = acc;
    }
    __syncthreads();
    float m = -1e30f;
    for (int c = tid; c < C_; c += 512) m = fmaxf(m, y[c]);
    red[tid] = m;
    __syncthreads();
    for (int d = 256; d > 0; d >>= 1) {
        if (tid < d) red[tid] = fmaxf(red[tid], red[tid + d]);
        __syncthreads();
    }
    m = red[0];
    __syncthreads();
    float s = 0.f;
    for (int c = tid; c < C_; c += 512) s += __expf(y[c] - m);
    red[tid] = s;
    __syncthreads();
    for (int d = 256; d > 0; d >>= 1) {
        if (tid < d) red[tid] += red[tid + d];
        __syncthreads();
    }
    float lse = m + logf(red[0]);
    for (int c = tid; c < C_; c += 512) outp[(long)b*C_ + c] = y[c] - lse;
}

// ---------------- launch ----------------

extern "C" void kernel_launch(void* const* d_in, const int* in_sizes, int n_in,
                              void* d_out, int out_size, void* d_ws, size_t ws_size,
                              hipStream_t stream) {
    const float* x        = (const float*)d_in[0];
    const int*   ei       = (const int*)d_in[1];
    const float* gcn_w0   = (const float*)d_in[2];
    const float* gcn_w12  = (const float*)d_in[3];
    const float* gcn_b    = (const float*)d_in[4];
    const float* bn_gamma = (const float*)d_in[5];
    const float* bn_beta  = (const float*)d_in[6];
    const float* bn_mean  = (const float*)d_in[7];
    const float* bn_var   = (const float*)d_in[8];
    const float* wih0     = (const float*)d_in[9];
    const float* whh0     = (const float*)d_in[10];
    const float* bih0     = (const float*)d_in[11];
    const float* bhh0     = (const float*)d_in[12];
    const float* wih1     = (const float*)d_in[13];
    const float* whh1     = (const float*)d_in[14];
    const float* bih1     = (const float*)d_in[15];
    const float* bhh1     = (const float*)d_in[16];
    const float* attn_w1  = (const float*)d_in[17];
    const float* attn_b1  = (const float*)d_in[18];
    const float* attn_w2  = (const float*)d_in[19];
    const float* attn_b2  = (const float*)d_in[20];
    const float* fc1_w    = (const float*)d_in[21];
    const float* fc1_b    = (const float*)d_in[22];
    const float* fc2_w    = (const float*)d_in[23];
    const float* fc2_b    = (const float*)d_in[24];

    char* p = (char*)d_ws;
    auto alloc = [&](size_t bytes) {
        void* r = (void*)p;
        p += (bytes + 255) & ~(size_t)255;
        return r;
    };
    ushort* xb     = (ushort*)alloc((size_t)M_*FIN_*2);
    ushort* aggbuf = (ushort*)alloc((size_t)M_*H_*2);
    ushort* hbA    = (ushort*)alloc((size_t)M_*H_*2);
    ushort* hbB    = (ushort*)alloc((size_t)M_*H_*2);
    int*   cnt     = (int*)  alloc((size_t)M_*4);
    float* dinv    = (float*)alloc((size_t)M_*4);
    int*   bsum    = (int*)  alloc((size_t)SCAN_NB*4);
    int*   bexcl   = (int*)  alloc((size_t)SCAN_NB*4);
    int*   csr_off = (int*)  alloc((size_t)(M_+1)*4);
    int*   csr_cur = (int*)  alloc((size_t)M_*4);
    int*   csr_src = (int*)  alloc((size_t)TE_*4);
    float* bn_sc   = (float*)alloc(384*4);
    float* bn_sh   = (float*)alloc(384*4);
    float* bias0   = (float*)alloc(1024*4);
    float* bias1   = (float*)alloc(1024*4);
    ushort* w0t    = (ushort*)alloc((size_t)128*16*2);
    ushort* w1t    = (ushort*)alloc((size_t)128*128*2);
    ushort* w2t    = (ushort*)alloc((size_t)128*128*2);
    unsigned int* wpk0 = (unsigned int*)alloc((size_t)2*64*512*4);
    unsigned int* wpk1 = (unsigned int*)alloc((size_t)2*64*512*4);
    ushort* wih0b  = (ushort*)alloc((size_t)2*512*128*2);
    ushort* wih1b  = (ushort*)alloc((size_t)2*512*256*2);
    ushort* embb   = (ushort*)alloc((size_t)T_*B_*H_*2);
    float* pre     = (float*)alloc((size_t)2*T_*B_*512*4);
    float* out1    = (float*)alloc((size_t)T_*B_*256*4);
    ushort* out1b  = (ushort*)alloc((size_t)T_*B_*256*2);
    float* out2v   = (float*)alloc((size_t)T_*B_*256*4);
    ushort* out2b  = (ushort*)alloc((size_t)T_*B_*256*2);
    float* attn_av = (float*)alloc((size_t)B_*T_*4);
    float* wsv     = (float*)alloc((size_t)B_*256*4);

    // --- graph preprocessing (CSR by dst) ---
    hipMemsetAsync(cnt, 0, (size_t)M_*4, stream);
    hipMemsetAsync(csr_cur, 0, (size_t)M_*4, stream);
    count_edges_k<<<(TE_+255)/256, 256, 0, stream>>>(ei, cnt);
    scan1_k<<<SCAN_NB, 256, 0, stream>>>(cnt, bsum, dinv);
    scan2_k<<<1, 256, 0, stream>>>(bsum, bexcl, csr_off);
    scan3_k<<<SCAN_NB, 256, 0, stream>>>(cnt, bexcl, csr_off);
    fill_k<<<(TE_+255)/256, 256, 0, stream>>>(ei, csr_off, csr_cur, csr_src);

    // --- weight prep (merged) ---
    wprep_k<<<(WPREP_TOTAL+255)/256, 256, 0, stream>>>(
        gcn_b, bn_gamma, bn_beta, bn_mean, bn_var, bn_sc, bn_sh,
        bih0, bhh0, bias0, bih1, bhh1, bias1,
        gcn_w0, gcn_w12, w0t, w1t, w2t,
        whh0, whh1, wpk0, wpk1,
        wih0, wih1, wih0b, wih1b);
    convx_k<<<(M_*FIN_/4 + 255)/256, 256, 0, stream>>>(x, xb);

    // --- GCN layer 0 ---
    gather16_k<<<M_/32, 256, 0, stream>>>(xb, aggbuf, csr_off, csr_src, dinv);
    mm_mfma_k<16, false><<<M_/64, 256, 0, stream>>>(aggbuf, w0t, hbA,
                                                    bn_sc + 0, bn_sh + 0, nullptr);
    // --- GCN layer 1 ---
    gather128_k<<<dim3(M_/16, 2), 256, 0, stream>>>(hbA, aggbuf, csr_off, csr_src, dinv);
    mm_mfma_k<128, true><<<M_/64, 256, 0, stream>>>(aggbuf, w1t, hbB,
                                                    bn_sc + 128, bn_sh + 128, hbA);
    // --- GCN layer 2 ---
    gather128_k<<<dim3(M_/16, 2), 256, 0, stream>>>(hbB, aggbuf, csr_off, csr_src, dinv);
    mm_mfma_k<128, true><<<M_/64, 256, 0, stream>>>(aggbuf, w2t, hbA,
                                                    bn_sc + 256, bn_sh + 256, hbB);

    // --- mean pool -> embb [T*B,128] bf16 ---
    meanpool_k<<<T_*B_, 128, 0, stream>>>(hbA, embb);

    // --- BiLSTM layer 0 ---
    mm_pre_k<128><<<dim3((T_*B_)/64, 4, 2), 256, 0, stream>>>(embb, wih0b, pre, bias0);
    lstm_scan_k<<<64, 512, 0, stream>>>(pre, wpk0, out1, out1b);

    // --- BiLSTM layer 1 ---
    mm_pre_k<256><<<dim3((T_*B_)/64, 4, 2), 256, 0, stream>>>(out1b, wih1b, pre, bias1);
    lstm_scan_k<<<64, 512, 0, stream>>>(pre, wpk1, out2v, out2b);

    // --- attention ---
    attn_a_k<<<T_*B_, 128, 0, stream>>>(out2v, attn_w1, attn_b1, attn_w2, attn_b2, attn_av);
    attn_pool_k<<<B_, 256, 0, stream>>>(out2v, attn_av, wsv);

    // --- head ---
    head_k<<<B_, 512, 0, stream>>>(wsv, fc1_w, fc1_b, fc2_w, fc2_b, (float*)d_out);
}

// Round 5
// 480.353 us; speedup vs baseline: 3.1518x; 1.1245x over previous
//
#include <hip/hip_runtime.h>

#define T_ 48
#define B_ 32
#define N_ 96
#define E_ 24576
#define BN_ (B_*N_)      // 3072
#define M_ (T_*BN_)      // 147456
#define FIN_ 16
#define H_ 128
#define C_ 500
#define TE_ (T_*E_)      // 1179648
#define EPS_ 1e-5f
#define SCAN_NB (M_/256) // 576

typedef __bf16 bf16x8 __attribute__((ext_vector_type(8)));
typedef float  f32x4  __attribute__((ext_vector_type(4)));
typedef _Float16 half2v __attribute__((ext_vector_type(2)));

__device__ __forceinline__ float bf2f(ushort u) {
    union { unsigned int i; float f; } v;
    v.i = ((unsigned int)u) << 16;
    return v.f;
}
__device__ __forceinline__ ushort f2bf(float f) {
    union { float f; unsigned int i; } v;
    v.f = f;
    unsigned int u = v.i;
    unsigned int r = (u + 0x7fffu + ((u >> 16) & 1u)) >> 16;
    return (ushort)r;
}
__device__ __forceinline__ ushort f2h(float f) {
    _Float16 h = (_Float16)f;
    union { _Float16 h; ushort u; } v;
    v.h = h;
    return v.u;
}
__device__ __forceinline__ float dot2pk(unsigned int hbits, unsigned int wbits, float acc) {
#if __has_builtin(__builtin_amdgcn_fdot2)
    return __builtin_amdgcn_fdot2(__builtin_bit_cast(half2v, hbits),
                                  __builtin_bit_cast(half2v, wbits), acc, false);
#else
    half2v hv = __builtin_bit_cast(half2v, hbits);
    half2v wv = __builtin_bit_cast(half2v, wbits);
    acc = fmaf((float)hv[0], (float)wv[0], acc);
    acc = fmaf((float)hv[1], (float)wv[1], acc);
    return acc;
#endif
}
__device__ __forceinline__ float sigm(float x) {
    return 1.f / (1.f + __expf(-x));
}
__device__ __forceinline__ float ftanh(float x) {
    x = fminf(15.f, fmaxf(-15.f, x));
    float e = __expf(2.f * x);
    return (e - 1.f) / (e + 1.f);
}

// ---------------- graph preprocessing ----------------

__global__ void count_edges_k(const int* __restrict__ ei, int* __restrict__ cnt) {
    int i = blockIdx.x * blockDim.x + threadIdx.x;
    if (i >= TE_) return;
    int t = i / E_, e = i % E_;
    int dst = ei[(t*2+1)*E_ + e] + t*BN_;
    atomicAdd(&cnt[dst], 1);
}

// block reduction of cnt + dinv computation
__global__ void scan1_k(const int* __restrict__ cnt, int* __restrict__ bsum,
                        float* __restrict__ dinv) {
    __shared__ int s[256];
    int i = blockIdx.x*256 + threadIdx.x;
    int v = cnt[i];
    dinv[i] = rsqrtf((float)v + 1.0f);
    s[threadIdx.x] = v;
    __syncthreads();
    for (int d = 128; d > 0; d >>= 1) {
        if (threadIdx.x < d) s[threadIdx.x] += s[threadIdx.x + d];
        __syncthreads();
    }
    if (threadIdx.x == 0) bsum[blockIdx.x] = s[0];
}

// parallel single-block scan over SCAN_NB block sums
__global__ __launch_bounds__(256) void scan2_k(const int* __restrict__ bsum,
                                               int* __restrict__ bexcl,
                                               int* __restrict__ csr_off) {
    __shared__ int part[256];
    int tid = threadIdx.x;
    int base = tid*3;   // 256*3 = 768 >= 576
    int a = (base   < SCAN_NB) ? bsum[base]   : 0;
    int b = (base+1 < SCAN_NB) ? bsum[base+1] : 0;
    int c = (base+2 < SCAN_NB) ? bsum[base+2] : 0;
    int tot = a + b + c;
    part[tid] = tot;
    __syncthreads();
    for (int d = 1; d < 256; d <<= 1) {
        int add = (tid >= d) ? part[tid - d] : 0;
        __syncthreads();
        part[tid] += add;
        __syncthreads();
    }
    int excl = part[tid] - tot;
    if (base   < SCAN_NB) bexcl[base]   = excl;
    if (base+1 < SCAN_NB) bexcl[base+1] = excl + a;
    if (base+2 < SCAN_NB) bexcl[base+2] = excl + a + b;
    if (tid == 255) csr_off[M_] = part[255];
}

__global__ void scan3_k(const int* __restrict__ cnt, const int* __restrict__ bexcl,
                        int* __restrict__ csr_off) {
    __shared__ int s[256];
    int i = blockIdx.x*256 + threadIdx.x;
    int v = cnt[i];
    s[threadIdx.x] = v;
    __syncthreads();
    for (int d = 1; d < 256; d <<= 1) {
        int add = (threadIdx.x >= d) ? s[threadIdx.x - d] : 0;
        __syncthreads();
        s[threadIdx.x] += add;
        __syncthreads();
    }
    csr_off[i] = bexcl[blockIdx.x] + s[threadIdx.x] - v;  // exclusive
}

__global__ void fill_k(const int* __restrict__ ei, const int* __restrict__ csr_off,
                       int* __restrict__ cur, int* __restrict__ csr_src) {
    int i = blockIdx.x * blockDim.x + threadIdx.x;
    if (i >= TE_) return;
    int t = i / E_, e = i % E_;
    int src = ei[(t*2+0)*E_ + e] + t*BN_;
    int dst = ei[(t*2+1)*E_ + e] + t*BN_;
    int pos = atomicAdd(&cur[dst], 1);
    csr_src[csr_off[dst] + pos] = src;
}

// ---------------- conversions / merged weight prep ----------------

__global__ void convx_k(const float* __restrict__ in, ushort* __restrict__ out) {
    int i = blockIdx.x * blockDim.x + threadIdx.x;   // one per 4 elems
    if (i >= M_*FIN_/4) return;
    float4 v = *(const float4*)&in[i*4];
    ushort4 o;
    o.x = f2bf(v.x); o.y = f2bf(v.y); o.z = f2bf(v.z); o.w = f2bf(v.w);
    *(ushort4*)&out[i*4] = o;
}

// one kernel for all small weight preparation
// wpk0/wpk1 are now packed f16 pairs [2][64][512]
#define WPREP_TOTAL (384+1024+2048+16384+16384+65536+65536+131072+262144)
__global__ void wprep_k(
    const float* __restrict__ gcn_b, const float* __restrict__ gam,
    const float* __restrict__ bet, const float* __restrict__ mu,
    const float* __restrict__ var,
    float* __restrict__ bn_sc, float* __restrict__ bn_sh,
    const float* __restrict__ bih0, const float* __restrict__ bhh0,
    float* __restrict__ bias0,
    const float* __restrict__ bih1, const float* __restrict__ bhh1,
    float* __restrict__ bias1,
    const float* __restrict__ gcn_w0, const float* __restrict__ gcn_w12,
    ushort* __restrict__ w0t, ushort* __restrict__ w1t, ushort* __restrict__ w2t,
    const float* __restrict__ whh0, const float* __restrict__ whh1,
    unsigned int* __restrict__ wpk0, unsigned int* __restrict__ wpk1,
    const float* __restrict__ wih0, const float* __restrict__ wih1,
    ushort* __restrict__ wih0b, ushort* __restrict__ wih1b)
{
    int i = blockIdx.x * blockDim.x + threadIdx.x;
    if (i >= WPREP_TOTAL) return;
    if (i < 384) {
        float sc = gam[i] * rsqrtf(var[i] + EPS_);
        bn_sc[i] = sc;
        bn_sh[i] = gcn_b[i]*sc + bet[i] - mu[i]*sc;
        return;
    }
    i -= 384;
    if (i < 1024) {
        bias0[i] = bih0[i] + bhh0[i];
        bias1[i] = bih1[i] + bhh1[i];
        return;
    }
    i -= 1024;
    if (i < 2048) {
        int k = i >> 7, c = i & 127;
        w0t[c*16 + k] = f2bf(gcn_w0[i]);
        return;
    }
    i -= 2048;
    if (i < 16384) {
        int k = i >> 7, c = i & 127;
        w1t[c*128 + k] = f2bf(gcn_w12[i]);
        return;
    }
    i -= 16384;
    if (i < 16384) {
        int k = i >> 7, c = i & 127;
        w2t[c*128 + k] = f2bf(gcn_w12[16384 + i]);
        return;
    }
    i -= 16384;
    if (i < 65536) {
        // i = (dir*64 + q)*512 + g  -> f16 pair (whh[g][2q], whh[g][2q+1])
        int g = i & 511;
        int qd = i >> 9;
        int dir = qd >> 6, q = qd & 63;
        const float* wr = whh0 + ((long)(dir*512 + g))*128 + 2*q;
        wpk0[i] = (unsigned int)f2h(wr[0]) | ((unsigned int)f2h(wr[1]) << 16);
        return;
    }
    i -= 65536;
    if (i < 65536) {
        int g = i & 511;
        int qd = i >> 9;
        int dir = qd >> 6, q = qd & 63;
        const float* wr = whh1 + ((long)(dir*512 + g))*128 + 2*q;
        wpk1[i] = (unsigned int)f2h(wr[0]) | ((unsigned int)f2h(wr[1]) << 16);
        return;
    }
    i -= 65536;
    if (i < 131072) {
        wih0b[i] = f2bf(wih0[i]);
        return;
    }
    i -= 131072;
    wih1b[i] = f2bf(wih1[i]);
}

// ---------------- bf16 gathers (XCD-chunk swizzled, ILP-unrolled) ----------------

__global__ __launch_bounds__(256) void gather128_k(
    const ushort* __restrict__ h, ushort* __restrict__ out,
    const int* __restrict__ csr_off, const int* __restrict__ csr_src,
    const float* __restrict__ dinv)
{
    int nb = gridDim.x;                  // M/16, divisible by 8
    int chunk = nb >> 3;
    int bswz = (blockIdx.x & 7) * chunk + (blockIdx.x >> 3);
    int node = bswz * 16 + (threadIdx.x >> 4);
    int f0 = blockIdx.y * 64 + (threadIdx.x & 15) * 4;
    float dv = dinv[node];
    ushort4 sv = *(const ushort4*)(h + (long)node*128 + f0);
    float s = dv * dv;
    float a0 = bf2f(sv.x)*s, a1 = bf2f(sv.y)*s, a2 = bf2f(sv.z)*s, a3 = bf2f(sv.w)*s;
    int e0 = csr_off[node], e1 = csr_off[node+1];
    int j = e0;
    for (; j + 4 <= e1; j += 4) {
        int s0 = csr_src[j], s1 = csr_src[j+1], s2 = csr_src[j+2], s3 = csr_src[j+3];
        float d0 = dinv[s0], d1 = dinv[s1], d2 = dinv[s2], d3 = dinv[s3];
        ushort4 v0 = *(const ushort4*)(h + (long)s0*128 + f0);
        ushort4 v1 = *(const ushort4*)(h + (long)s1*128 + f0);
        ushort4 v2 = *(const ushort4*)(h + (long)s2*128 + f0);
        ushort4 v3 = *(const ushort4*)(h + (long)s3*128 + f0);
        d0 *= dv; d1 *= dv; d2 *= dv; d3 *= dv;
        a0 += bf2f(v0.x)*d0 + bf2f(v1.x)*d1 + bf2f(v2.x)*d2 + bf2f(v3.x)*d3;
        a1 += bf2f(v0.y)*d0 + bf2f(v1.y)*d1 + bf2f(v2.y)*d2 + bf2f(v3.y)*d3;
        a2 += bf2f(v0.z)*d0 + bf2f(v1.z)*d1 + bf2f(v2.z)*d2 + bf2f(v3.z)*d3;
        a3 += bf2f(v0.w)*d0 + bf2f(v1.w)*d1 + bf2f(v2.w)*d2 + bf2f(v3.w)*d3;
    }
    for (; j < e1; j++) {
        int sc = csr_src[j];
        float en = dinv[sc] * dv;
        ushort4 v = *(const ushort4*)(h + (long)sc*128 + f0);
        a0 += bf2f(v.x)*en; a1 += bf2f(v.y)*en; a2 += bf2f(v.z)*en; a3 += bf2f(v.w)*en;
    }
    ushort4 o;
    o.x = f2bf(a0); o.y = f2bf(a1); o.z = f2bf(a2); o.w = f2bf(a3);
    *(ushort4*)(out + (long)node*128 + f0) = o;
}

__global__ __launch_bounds__(256) void gather16_k(
    const ushort* __restrict__ h, ushort* __restrict__ out,
    const int* __restrict__ csr_off, const int* __restrict__ csr_src,
    const float* __restrict__ dinv)
{
    int nb = gridDim.x;                  // M/32
    int chunk = nb >> 3;
    int bswz = (blockIdx.x & 7) * chunk + (blockIdx.x >> 3);
    int node = bswz * 32 + (threadIdx.x >> 3);
    int f0 = (threadIdx.x & 7) * 2;
    float dv = dinv[node];
    ushort2 sv = *(const ushort2*)(h + (long)node*16 + f0);
    float s = dv * dv;
    float a0 = bf2f(sv.x)*s, a1 = bf2f(sv.y)*s;
    int e0 = csr_off[node], e1 = csr_off[node+1];
    int j = e0;
    for (; j + 4 <= e1; j += 4) {
        int s0 = csr_src[j], s1 = csr_src[j+1], s2 = csr_src[j+2], s3 = csr_src[j+3];
        float d0 = dinv[s0], d1 = dinv[s1], d2 = dinv[s2], d3 = dinv[s3];
        ushort2 v0 = *(const ushort2*)(h + (long)s0*16 + f0);
        ushort2 v1 = *(const ushort2*)(h + (long)s1*16 + f0);
        ushort2 v2 = *(const ushort2*)(h + (long)s2*16 + f0);
        ushort2 v3 = *(const ushort2*)(h + (long)s3*16 + f0);
        d0 *= dv; d1 *= dv; d2 *= dv; d3 *= dv;
        a0 += bf2f(v0.x)*d0 + bf2f(v1.x)*d1 + bf2f(v2.x)*d2 + bf2f(v3.x)*d3;
        a1 += bf2f(v0.y)*d0 + bf2f(v1.y)*d1 + bf2f(v2.y)*d2 + bf2f(v3.y)*d3;
    }
    for (; j < e1; j++) {
        int sc = csr_src[j];
        float en = dinv[sc] * dv;
        ushort2 v = *(const ushort2*)(h + (long)sc*16 + f0);
        a0 += bf2f(v.x)*en; a1 += bf2f(v.y)*en;
    }
    ushort2 o;
    o.x = f2bf(a0); o.y = f2bf(a1);
    *(ushort2*)(out + (long)node*16 + f0) = o;
}

// ---------------- MFMA GEMM: GCN layers (BN+ReLU+resid epilogue) ----------------
template<int K, bool HASRES>
__global__ __launch_bounds__(256) void mm_mfma_k(
    const ushort* __restrict__ A, const ushort* __restrict__ Wt,
    ushort* __restrict__ Cout,
    const float* __restrict__ bnsc, const float* __restrict__ bnsh,
    const ushort* __restrict__ resid)
{
    int tid = threadIdx.x;
    int w = tid >> 6, lane = tid & 63;
    int l16 = lane & 15, lh = lane >> 4;
    int row0 = blockIdx.x * 64 + w * 16;

    f32x4 acc[8];
    #pragma unroll
    for (int i = 0; i < 8; i++) acc[i] = (f32x4){0.f, 0.f, 0.f, 0.f};

    #pragma unroll
    for (int k0 = 0; k0 < K; k0 += 32) {
        int ka = k0 + lh*8;
        bf16x8 af;
        bool valid = (K >= 32) || (ka < K);
        if (valid) {
            af = *reinterpret_cast<const bf16x8*>(&A[(long)(row0 + l16)*K + ka]);
        } else {
            #pragma unroll
            for (int e = 0; e < 8; e++) af[e] = (__bf16)0.f;
        }
        #pragma unroll
        for (int ct = 0; ct < 8; ct++) {
            bf16x8 bfr;
            if (valid) {
                bfr = *reinterpret_cast<const bf16x8*>(&Wt[(long)(ct*16 + l16)*K + ka]);
            } else {
                #pragma unroll
                for (int e = 0; e < 8; e++) bfr[e] = (__bf16)0.f;
            }
            acc[ct] = __builtin_amdgcn_mfma_f32_16x16x32_bf16(af, bfr, acc[ct], 0, 0, 0);
        }
    }

    #pragma unroll
    for (int ct = 0; ct < 8; ct++) {
        int col = ct*16 + l16;
        float sc = bnsc[col], sh = bnsh[col];
        #pragma unroll
        for (int r = 0; r < 4; r++) {
            int row = row0 + lh*4 + r;
            float v = acc[ct][r] * sc + sh;
            v = fmaxf(v, 0.f);
            if (HASRES) v += bf2f(resid[(long)row*128 + col]);
            Cout[(long)row*128 + col] = f2bf(v);
        }
    }
}

// ---------------- MFMA GEMM: LSTM input projection (both dirs via blockIdx.z) ----
template<int K>
__global__ __launch_bounds__(256) void mm_pre_k(
    const ushort* __restrict__ A, const ushort* __restrict__ Wt_all,
    float* __restrict__ Cout_all, const float* __restrict__ bias_all)
{
    int dir = blockIdx.z;
    const ushort* Wt = Wt_all + (size_t)dir * 512 * K;
    float* Cout = Cout_all + (size_t)dir * T_ * B_ * 512;
    const float* bias = bias_all + dir * 512;

    int tid = threadIdx.x;
    int w = tid >> 6, lane = tid & 63;
    int l16 = lane & 15, lh = lane >> 4;
    int row0 = blockIdx.x * 64 + w * 16;
    int c0 = blockIdx.y * 128;

    f32x4 acc[8];
    #pragma unroll
    for (int i = 0; i < 8; i++) acc[i] = (f32x4){0.f, 0.f, 0.f, 0.f};

    #pragma unroll
    for (int k0 = 0; k0 < K; k0 += 32) {
        int ka = k0 + lh*8;
        bf16x8 af = *reinterpret_cast<const bf16x8*>(&A[(long)(row0 + l16)*K + ka]);
        #pragma unroll
        for (int ct = 0; ct < 8; ct++) {
            bf16x8 bfr = *reinterpret_cast<const bf16x8*>(&Wt[(long)(c0 + ct*16 + l16)*K + ka]);
            acc[ct] = __builtin_amdgcn_mfma_f32_16x16x32_bf16(af, bfr, acc[ct], 0, 0, 0);
        }
    }

    #pragma unroll
    for (int ct = 0; ct < 8; ct++) {
        int col = c0 + ct*16 + l16;
        float bv = bias[col];
        #pragma unroll
        for (int r = 0; r < 4; r++) {
            int row = row0 + lh*4 + r;
            Cout[(long)row*512 + col] = acc[ct][r] + bv;
        }
    }
}

// ---------------- mean pool (bf16 in, bf16 out) ----------------

__global__ void meanpool_k(const ushort* __restrict__ h, ushort* __restrict__ embb) {
    int row = blockIdx.x;            // t*B + b
    int t = row / B_, b = row - t*B_;
    int hh = threadIdx.x;
    const ushort* base = h + ((long)t*BN_ + b*N_)*H_ + hh;
    float acc = 0.f;
    for (int n = 0; n < N_; n++) acc += bf2f(base[(long)n*H_]);
    embb[(long)row*H_ + hh] = f2bf(acc * (1.f / N_));
}

// ---------------- LSTM scan: f16 dot2, k-split x2, pre-prefetch ----------------
// grid = 2 dirs * 32 batch = 64 blocks, 1024 threads.
// thread = (half = tid>>9, g = tid&511); computes 64-wide partial of gate g.
__global__ __launch_bounds__(1024) void lstm_scan_k(
    const float* __restrict__ pre,            // [2][T*B][512]
    const unsigned int* __restrict__ wpkbuf,  // [2][64][512] packed f16 pairs
    float* __restrict__ out,                  // [T*B][256] f32
    ushort* __restrict__ outb)                // [T*B][256] bf16
{
    int dir = blockIdx.x >> 5;
    int b   = blockIdx.x & 31;
    int tid = threadIdx.x;
    int half = tid >> 9;
    int g    = tid & 511;

    __shared__ ushort h_s[H_];               // f16 bits
    __shared__ float part[1024];
    if (tid < H_) h_s[tid] = 0;
    float creg = 0.f;                        // threads tid<128 own c[g]

    // preload whh f16-pair block: 32 packed uints (64 k values)
    const unsigned int* wp = wpkbuf + (long)dir * 64 * 512 + (long)half * 32 * 512;
    unsigned int wpk[32];
    #pragma unroll
    for (int q = 0; q < 32; q++) wpk[q] = wp[q*512 + g];

    const float* pred = pre + (long)dir * T_ * B_ * 512;
    int t = dir ? (T_ - 1) : 0;
    int tstep = dir ? -1 : 1;
    float pv = (half == 0) ? pred[((long)t*B_ + b)*512 + g] : 0.f;
    __syncthreads();

    for (int st = 0; st < T_; st++) {
        // prefetch next step's gate bias (hidden under this step's compute)
        int tn = t + tstep;
        tn = (tn < 0) ? 0 : ((tn >= T_) ? T_ - 1 : tn);
        float pvn = (half == 0) ? pred[((long)tn*B_ + b)*512 + g] : 0.f;

        // partial dot over 64 h-values (32 f16 pairs)
        const uint4* h4 = (const uint4*)(h_s + half*64);
        float acc = pv;
        #pragma unroll
        for (int jj = 0; jj < 8; jj++) {
            uint4 hv = h4[jj];
            acc = dot2pk(hv.x, wpk[jj*4+0], acc);
            acc = dot2pk(hv.y, wpk[jj*4+1], acc);
            acc = dot2pk(hv.z, wpk[jj*4+2], acc);
            acc = dot2pk(hv.w, wpk[jj*4+3], acc);
        }
        part[tid] = acc;
        __syncthreads();

        if (tid < H_) {
            float ig = sigm (part[tid]       + part[512 + tid]);
            float fg = sigm (part[128 + tid] + part[640 + tid]);
            float gg = ftanh(part[256 + tid] + part[768 + tid]);
            float og = sigm (part[384 + tid] + part[896 + tid]);
            float c = fg * creg + ig * gg;
            float h = og * ftanh(c);
            creg = c;
            h_s[tid] = f2h(h);
            long orow = ((long)t*B_ + b)*256 + dir*H_ + tid;
            out[orow] = h;
            outb[orow] = f2bf(h);
        }
        __syncthreads();
        pv = pvn;
        t = tn;
    }
}

// ---------------- attention ----------------

__global__ __launch_bounds__(128) void attn_a_k(
    const float* __restrict__ out2, const float* __restrict__ w1,
    const float* __restrict__ b1, const float* __restrict__ w2,
    const float* __restrict__ b2v, float* __restrict__ a)
{
    int row = blockIdx.x;
    int j = threadIdx.x;
    const float* xr = out2 + (long)row * 256;
    float acc = b1[j];
    for (int k = 0; k < 256; k++) acc += xr[k] * w1[k*128 + j];
    float u = tanhf(acc) * w2[j];
    __shared__ float red[128];
    red[j] = u;
    __syncthreads();
    for (int d = 64; d > 0; d >>= 1) {
        if (j < d) red[j] += red[j + d];
        __syncthreads();
    }
    if (j == 0) {
        int t = row / B_, b = row - t*B_;
        a[b*T_ + t] = red[0] + b2v[0];
    }
}

__global__ __launch_bounds__(256) void attn_pool_k(
    const float* __restrict__ out2, const float* __restrict__ a,
    float* __restrict__ wsv)
{
    int b = blockIdx.x;
    __shared__ float w[T_];
    if (threadIdx.x == 0) {
        float m = -1e30f;
        for (int t = 0; t < T_; t++) m = fmaxf(m, a[b*T_ + t]);
        float s = 0.f;
        for (int t = 0; t < T_; t++) { float e = __expf(a[b*T_ + t] - m); w[t] = e; s += e; }
        float inv = 1.f / s;
        for (int t = 0; t < T_; t++) w[t] *= inv;
    }
    __syncthreads();
    int h2 = threadIdx.x;
    float acc = 0.f;
    for (int t = 0; t < T_; t++) acc += w[t] * out2[((long)t*B_ + b)*256 + h2];
    wsv[b*256 + h2] = acc;
}

// ---------------- FC head + log_softmax ----------------

__global__ __launch_bounds__(512) void head_k(
    const float* __restrict__ wsv, const float* __restrict__ w1,
    const float* __restrict__ b1, const float* __restrict__ w2,
    const float* __restrict__ b2, float* __restrict__ outp)
{
    int b = blockIdx.x;
    int tid = threadIdx.x;
    __shared__ float r[128];
    __shared__ float y[C_];
    __shared__ float red[512];
    if (tid < 128) {
        float acc = b1[tid];
        for (int k = 0; k < 256; k++) acc += wsv[b*256 + k] * w1[k*128 + tid];
        r[tid] = fmaxf(acc, 0.f);
    }
    __syncthreads();
    for (int c = tid; c < C_; c += 512) {
        float acc = b2[c];
        for (int k = 0; k < 128; k++) acc += r[k] * w2[k*C_ + c];
        y[c] = acc;
    }
    __syncthreads();
    float m = -1e30f;
    for (int c = tid; c < C_; c += 512) m = fmaxf(m, y[c]);
    red[tid] = m;
    __syncthreads();
    for (int d = 256; d > 0; d >>= 1) {
        if (tid < d) red[tid] = fmaxf(red[tid], red[tid + d]);
        __syncthreads();
    }
    m = red[0];
    __syncthreads();
    float s = 0.f;
    for (int c = tid; c < C_; c += 512) s += __expf(y[c] - m);
    red[tid] = s;
    __syncthreads();
    for (int d = 256; d > 0; d >>= 1) {
        if (tid < d) red[tid] += red[tid + d];
        __syncthreads();
    }
    float lse = m + logf(red[0]);
    for (int c = tid; c < C_; c += 512) outp[(long)b*C_ + c] = y[c] - lse;
}

// ---------------- launch ----------------

extern "C" void kernel_launch(void* const* d_in, const int* in_sizes, int n_in,
                              void* d_out, int out_size, void* d_ws, size_t ws_size,
                              hipStream_t stream) {
    const float* x        = (const float*)d_in[0];
    const int*   ei       = (const int*)d_in[1];
    const float* gcn_w0   = (const float*)d_in[2];
    const float* gcn_w12  = (const float*)d_in[3];
    const float* gcn_b    = (const float*)d_in[4];
    const float* bn_gamma = (const float*)d_in[5];
    const float* bn_beta  = (const float*)d_in[6];
    const float* bn_mean  = (const float*)d_in[7];
    const float* bn_var   = (const float*)d_in[8];
    const float* wih0     = (const float*)d_in[9];
    const float* whh0     = (const float*)d_in[10];
    const float* bih0     = (const float*)d_in[11];
    const float* bhh0     = (const float*)d_in[12];
    const float* wih1     = (const float*)d_in[13];
    const float* whh1     = (const float*)d_in[14];
    const float* bih1     = (const float*)d_in[15];
    const float* bhh1     = (const float*)d_in[16];
    const float* attn_w1  = (const float*)d_in[17];
    const float* attn_b1  = (const float*)d_in[18];
    const float* attn_w2  = (const float*)d_in[19];
    const float* attn_b2  = (const float*)d_in[20];
    const float* fc1_w    = (const float*)d_in[21];
    const float* fc1_b    = (const float*)d_in[22];
    const float* fc2_w    = (const float*)d_in[23];
    const float* fc2_b    = (const float*)d_in[24];

    char* p = (char*)d_ws;
    auto alloc = [&](size_t bytes) {
        void* r = (void*)p;
        p += (bytes + 255) & ~(size_t)255;
        return r;
    };
    ushort* xb     = (ushort*)alloc((size_t)M_*FIN_*2);
    ushort* aggbuf = (ushort*)alloc((size_t)M_*H_*2);
    ushort* hbA    = (ushort*)alloc((size_t)M_*H_*2);
    ushort* hbB    = (ushort*)alloc((size_t)M_*H_*2);
    int*   cnt     = (int*)  alloc((size_t)M_*4);
    float* dinv    = (float*)alloc((size_t)M_*4);
    int*   bsum    = (int*)  alloc((size_t)SCAN_NB*4);
    int*   bexcl   = (int*)  alloc((size_t)SCAN_NB*4);
    int*   csr_off = (int*)  alloc((size_t)(M_+1)*4);
    int*   csr_cur = (int*)  alloc((size_t)M_*4);
    int*   csr_src = (int*)  alloc((size_t)TE_*4);
    float* bn_sc   = (float*)alloc(384*4);
    float* bn_sh   = (float*)alloc(384*4);
    float* bias0   = (float*)alloc(1024*4);
    float* bias1   = (float*)alloc(1024*4);
    ushort* w0t    = (ushort*)alloc((size_t)128*16*2);
    ushort* w1t    = (ushort*)alloc((size_t)128*128*2);
    ushort* w2t    = (ushort*)alloc((size_t)128*128*2);
    unsigned int* wpk0 = (unsigned int*)alloc((size_t)2*64*512*4);
    unsigned int* wpk1 = (unsigned int*)alloc((size_t)2*64*512*4);
    ushort* wih0b  = (ushort*)alloc((size_t)2*512*128*2);
    ushort* wih1b  = (ushort*)alloc((size_t)2*512*256*2);
    ushort* embb   = (ushort*)alloc((size_t)T_*B_*H_*2);
    float* pre     = (float*)alloc((size_t)2*T_*B_*512*4);
    float* out1    = (float*)alloc((size_t)T_*B_*256*4);
    ushort* out1b  = (ushort*)alloc((size_t)T_*B_*256*2);
    float* out2v   = (float*)alloc((size_t)T_*B_*256*4);
    ushort* out2b  = (ushort*)alloc((size_t)T_*B_*256*2);
    float* attn_av = (float*)alloc((size_t)B_*T_*4);
    float* wsv     = (float*)alloc((size_t)B_*256*4);

    // --- graph preprocessing (CSR by dst) ---
    hipMemsetAsync(cnt, 0, (size_t)M_*4, stream);
    hipMemsetAsync(csr_cur, 0, (size_t)M_*4, stream);
    count_edges_k<<<(TE_+255)/256, 256, 0, stream>>>(ei, cnt);
    scan1_k<<<SCAN_NB, 256, 0, stream>>>(cnt, bsum, dinv);
    scan2_k<<<1, 256, 0, stream>>>(bsum, bexcl, csr_off);
    scan3_k<<<SCAN_NB, 256, 0, stream>>>(cnt, bexcl, csr_off);
    fill_k<<<(TE_+255)/256, 256, 0, stream>>>(ei, csr_off, csr_cur, csr_src);

    // --- weight prep (merged) ---
    wprep_k<<<(WPREP_TOTAL+255)/256, 256, 0, stream>>>(
        gcn_b, bn_gamma, bn_beta, bn_mean, bn_var, bn_sc, bn_sh,
        bih0, bhh0, bias0, bih1, bhh1, bias1,
        gcn_w0, gcn_w12, w0t, w1t, w2t,
        whh0, whh1, wpk0, wpk1,
        wih0, wih1, wih0b, wih1b);
    convx_k<<<(M_*FIN_/4 + 255)/256, 256, 0, stream>>>(x, xb);

    // --- GCN layer 0 ---
    gather16_k<<<M_/32, 256, 0, stream>>>(xb, aggbuf, csr_off, csr_src, dinv);
    mm_mfma_k<16, false><<<M_/64, 256, 0, stream>>>(aggbuf, w0t, hbA,
                                                    bn_sc + 0, bn_sh + 0, nullptr);
    // --- GCN layer 1 ---
    gather128_k<<<dim3(M_/16, 2), 256, 0, stream>>>(hbA, aggbuf, csr_off, csr_src, dinv);
    mm_mfma_k<128, true><<<M_/64, 256, 0, stream>>>(aggbuf, w1t, hbB,
                                                    bn_sc + 128, bn_sh + 128, hbA);
    // --- GCN layer 2 ---
    gather128_k<<<dim3(M_/16, 2), 256, 0, stream>>>(hbB, aggbuf, csr_off, csr_src, dinv);
    mm_mfma_k<128, true><<<M_/64, 256, 0, stream>>>(aggbuf, w2t, hbA,
                                                    bn_sc + 256, bn_sh + 256, hbB);

    // --- mean pool -> embb [T*B,128] bf16 ---
    meanpool_k<<<T_*B_, 128, 0, stream>>>(hbA, embb);

    // --- BiLSTM layer 0 ---
    mm_pre_k<128><<<dim3((T_*B_)/64, 4, 2), 256, 0, stream>>>(embb, wih0b, pre, bias0);
    lstm_scan_k<<<64, 1024, 0, stream>>>(pre, wpk0, out1, out1b);

    // --- BiLSTM layer 1 ---
    mm_pre_k<256><<<dim3((T_*B_)/64, 4, 2), 256, 0, stream>>>(out1b, wih1b, pre, bias1);
    lstm_scan_k<<<64, 1024, 0, stream>>>(pre, wpk1, out2v, out2b);

    // --- attention ---
    attn_a_k<<<T_*B_, 128, 0, stream>>>(out2v, attn_w1, attn_b1, attn_w2, attn_b2, attn_av);
    attn_pool_k<<<B_, 256, 0, stream>>>(out2v, attn_av, wsv);

    // --- head ---
    head_k<<<B_, 512, 0, stream>>>(wsv, fc1_w, fc1_b, fc2_w, fc2_b, (float*)d_out);
}